// Round 1
// 464.456 us; speedup vs baseline: 1.0039x; 1.0039x over previous
//
#include <hip/hip_runtime.h>

typedef unsigned int u32;
typedef unsigned short u16;

#define N_TOK 1024
#define D_DIM 2048
#define F_DIM 5632
#define E_NUM 8
#define R_DIM 16
#define LSCALE 2.0f
#define FT 256            // f-columns per act block
#define NT (F_DIM / FT)   // 22 F-tiles
#define TC 8              // token chunks per expert
#define BN13 11520        // fused B rows: W1(5632) + W3(5632) + A1(128) + A3(128)

typedef __bf16 bf16x8 __attribute__((ext_vector_type(8)));
typedef float f32x4 __attribute__((ext_vector_type(4)));
typedef u16 u16x8 __attribute__((ext_vector_type(8)));

__device__ inline u16 f2bf(float f) {
    u32 u = __builtin_bit_cast(u32, f);
    u32 r = (u + 0x7fffu + ((u >> 16) & 1u)) >> 16;
    return (u16)r;
}
__device__ inline float bf2f(u16 h) {
    u32 u = ((u32)h) << 16;
    return __builtin_bit_cast(float, u);
}

// ---------------- fused fp32 -> bf16 conversion for ALL weight tensors (1 launch) ----
// Segment boundaries in float4 units (all multiples of 256 -> no intra-block divergence):
//   x:  [0,        524288)
//   W1: [524288,   3407872)
//   W3: [3407872,  6291456)
//   A1: [6291456,  6356992)
//   A3: [6356992,  6422528)
//   W2: [6422528,  9306112)
//   B1: [9306112,  9486336)
//   B3: [9486336,  9666560)
__global__ __launch_bounds__(256) void cvt_all(const float* __restrict__ x,
                                               const float* __restrict__ W1,
                                               const float* __restrict__ W3,
                                               const float* __restrict__ A1,
                                               const float* __restrict__ A3,
                                               const float* __restrict__ W2,
                                               const float* __restrict__ B1,
                                               const float* __restrict__ B3,
                                               u16* __restrict__ xb,
                                               u16* __restrict__ w13,
                                               u16* __restrict__ w2b,
                                               u16* __restrict__ b1b,
                                               u16* __restrict__ b3b) {
    int i = blockIdx.x * 256 + threadIdx.x;
    const float* src;
    u16* dst;
    int off;
    if (i < 524288)       { src = x;  dst = xb;             off = i; }
    else if (i < 3407872) { src = W1; dst = w13;            off = i - 524288; }
    else if (i < 6291456) { src = W3; dst = w13 + 11534336; off = i - 3407872; }
    else if (i < 6356992) { src = A1; dst = w13 + 23068672; off = i - 6291456; }
    else if (i < 6422528) { src = A3; dst = w13 + 23330816; off = i - 6356992; }
    else if (i < 9306112) { src = W2; dst = w2b;            off = i - 6422528; }
    else if (i < 9486336) { src = B1; dst = b1b;            off = i - 9306112; }
    else                  { src = B3; dst = b3b;            off = i - 9486336; }
    float4 v = ((const float4*)src)[off];
    union { u16 h[4]; ushort4 u4; } o;
    o.h[0] = f2bf(v.x); o.h[1] = f2bf(v.y); o.h[2] = f2bf(v.z); o.h[3] = f2bf(v.w);
    ((ushort4*)dst)[off] = o.u4;
}

// ---------------- A2 (E,R,F) fp32 -> A2t (E,F,R) bf16 ----------------
__global__ __launch_bounds__(256) void a2_transpose(const float* __restrict__ A2,
                                                    u16* __restrict__ A2t) {
    int e = blockIdx.y;
    int f = blockIdx.x * 256 + threadIdx.x;
    u16 row[16];
#pragma unroll
    for (int r = 0; r < 16; ++r)
        row[r] = f2bf(A2[((size_t)e * R_DIM + r) * F_DIM + f]);
    u16* dst = A2t + ((size_t)e * F_DIM + f) * 16;
#pragma unroll
    for (int q = 0; q < 2; ++q)
        ((ulonglong2*)dst)[q] = ((ulonglong2*)row)[q];
}

// ---------------- router: logits + softmax + top2 ----------------
__global__ __launch_bounds__(256) void router_kernel(const float* __restrict__ x,
                                                     const float* __restrict__ gw,
                                                     float* __restrict__ logits,
                                                     int* __restrict__ ridx,
                                                     float* __restrict__ rw) {
    int n = blockIdx.x;
    int tid = threadIdx.x;
    float part[E_NUM];
#pragma unroll
    for (int e = 0; e < E_NUM; ++e) part[e] = 0.f;
    const float* xr = x + (size_t)n * D_DIM;
    for (int d = tid; d < D_DIM; d += 256) {
        float xv = xr[d];
#pragma unroll
        for (int e = 0; e < E_NUM; ++e) part[e] += xv * gw[e * D_DIM + d];
    }
    __shared__ float sh[E_NUM][256];
#pragma unroll
    for (int e = 0; e < E_NUM; ++e) sh[e][tid] = part[e];
    __syncthreads();
    for (int off = 128; off > 0; off >>= 1) {
        if (tid < off) {
#pragma unroll
            for (int e = 0; e < E_NUM; ++e) sh[e][tid] += sh[e][tid + off];
        }
        __syncthreads();
    }
    if (tid == 0) {
        float lg[E_NUM], p[E_NUM];
        float mx = -1e30f;
        for (int e = 0; e < E_NUM; ++e) {
            lg[e] = sh[e][0];
            logits[n * E_NUM + e] = lg[e];
            if (lg[e] > mx) mx = lg[e];
        }
        float s = 0.f;
        for (int e = 0; e < E_NUM; ++e) { p[e] = expf(lg[e] - mx); s += p[e]; }
        for (int e = 0; e < E_NUM; ++e) p[e] /= s;
        int i1 = 0;
        for (int e = 1; e < E_NUM; ++e) if (p[e] > p[i1]) i1 = e;
        int i2 = (i1 == 0) ? 1 : 0;
        for (int e = 0; e < E_NUM; ++e) if (e != i1 && p[e] > p[i2]) i2 = e;
        float t = p[i1] + p[i2];
        ridx[n * 2] = i1; ridx[n * 2 + 1] = i2;
        rw[n * 2] = p[i1] / t; rw[n * 2 + 1] = p[i2] / t;
    }
}

// ---------------- expert token-list build ----------------
__global__ __launch_bounds__(64) void zero_counts(int* counts) {
    if (threadIdx.x < E_NUM) counts[threadIdx.x] = 0;
}
__global__ __launch_bounds__(256) void build_lists(const int* __restrict__ ridx,
                                                   int* __restrict__ counts,
                                                   u32* __restrict__ lists) {
    int n = blockIdx.x * 256 + threadIdx.x;
    if (n >= N_TOK) return;
#pragma unroll
    for (int k = 0; k < 2; ++k) {
        int e = ridx[n * 2 + k];
        int slot = atomicAdd(&counts[e], 1);
        lists[e * N_TOK + slot] = (u32)n | ((u32)k << 16);
    }
}

// ---------------- 256x256-tile bf16 MFMA GEMM, C[M,N] = A[M,K] @ B[N,K]^T -----------
// 512 threads = 8 waves (2 M x 4 N), each wave owns a 128x64 output sub-tile.
// Double-buffered 128 KiB LDS, T3 "minimal 2-phase": STAGE(next) issued BEFORE
// compute(cur), ONE barrier per K-step (the __syncthreads vmcnt drain doubles
// as the prefetch-complete wait).
// Bijective XCD-chunked blockIdx swizzle (m204): consecutive swizzled ids share
// a B panel and land on the same XCD's L2.
// mode: 0 = f32 store, 1 = bf16 store, 2 = f32 atomic add (split-K).
__global__ __launch_bounds__(512, 2) void gemm256(const u16* __restrict__ A,
                                                  const u16* __restrict__ B,
                                                  float* __restrict__ C,
                                                  int N, int K, int kslice,
                                                  int mode, int ntm, int ntn) {
    __shared__ __align__(16) u16 sA[2][256 * 64];
    __shared__ __align__(16) u16 sB[2][256 * 64];

    // --- bijective XCD-chunked swizzle ---
    const int nb = gridDim.x;
    const int f = blockIdx.x;
    const int q = nb >> 3, r = nb & 7;
    const int xcd = f & 7, lo = f >> 3;
    const int wg = (xcd < r ? xcd * (q + 1) : r * (q + 1) + (xcd - r) * q) + lo;

    const int mt = wg % ntm;
    const int t2 = wg / ntm;
    const int nt = t2 % ntn;
    const int zt = t2 / ntn;

    const int bm0 = mt * 256;
    const int bn0 = nt * 256;
    const int kb = zt * kslice;

    const int tid = threadIdx.x;
    const int lane = tid & 63;
    const int wave = tid >> 6;
    const int quad = lane >> 4;
    const int l16 = lane & 15;
    const int wm = (wave >> 2) * 128;   // 0 or 128
    const int wn = (wave & 3) * 64;     // 0,64,128,192

    f32x4 zero = {0.f, 0.f, 0.f, 0.f};
    f32x4 acc[8][4];
#pragma unroll
    for (int i = 0; i < 8; ++i)
#pragma unroll
        for (int j = 0; j < 4; ++j) acc[i][j] = zero;

    auto stage = [&](int buf, int k0) {
#pragma unroll
        for (int i = 0; i < 4; ++i) {
            int c = i * 512 + tid;      // 0..2047
            int rr = c >> 3;            // row 0..255
            int c8 = (c & 7) << 3;      // col 0..56
            const u16* ga = A + (size_t)(bm0 + rr) * K + k0 + c8;
            const u16* gb = B + (size_t)(bn0 + rr) * K + k0 + c8;
            __builtin_amdgcn_global_load_lds((const __attribute__((address_space(1))) u32*)ga,
                                             (__attribute__((address_space(3))) u32*)(&sA[buf][c * 8]),
                                             16, 0, 0);
            __builtin_amdgcn_global_load_lds((const __attribute__((address_space(1))) u32*)gb,
                                             (__attribute__((address_space(3))) u32*)(&sB[buf][c * 8]),
                                             16, 0, 0);
        }
    };

    const int nk = kslice >> 6;
    int cur = 0;
    stage(0, kb);
    __syncthreads();

    for (int kt = 0; kt < nk; ++kt) {
        if (kt + 1 < nk) stage(cur ^ 1, kb + (kt + 1) * 64);
#pragma unroll
        for (int ks = 0; ks < 2; ++ks) {
            bf16x8 af[8], bfv[4];
#pragma unroll
            for (int mi = 0; mi < 8; ++mi)
                af[mi] = *(const bf16x8*)(&sA[cur][(wm + mi * 16 + l16) * 64 + ks * 32 + quad * 8]);
#pragma unroll
            for (int ni = 0; ni < 4; ++ni)
                bfv[ni] = *(const bf16x8*)(&sB[cur][(wn + ni * 16 + l16) * 64 + ks * 32 + quad * 8]);
#pragma unroll
            for (int mi = 0; mi < 8; ++mi)
#pragma unroll
                for (int ni = 0; ni < 4; ++ni)
                    acc[mi][ni] = __builtin_amdgcn_mfma_f32_16x16x32_bf16(af[mi], bfv[ni],
                                                                          acc[mi][ni], 0, 0, 0);
        }
        __syncthreads();   // drains vmcnt(0): prefetch complete; all reads of cur done
        cur ^= 1;
    }

#pragma unroll
    for (int mi = 0; mi < 8; ++mi)
#pragma unroll
        for (int ni = 0; ni < 4; ++ni) {
            int col = bn0 + wn + ni * 16 + l16;
#pragma unroll
            for (int i = 0; i < 4; ++i) {
                int row = bm0 + wm + mi * 16 + quad * 4 + i;
                if (mode == 1) {
                    ((u16*)C)[(size_t)row * N + col] = f2bf(acc[mi][ni][i]);
                } else if (mode == 2) {
                    unsafeAtomicAdd(&C[(size_t)row * N + col], acc[mi][ni][i]);
                } else {
                    C[(size_t)row * N + col] = acc[mi][ni][i];
                }
            }
        }
}

// ---------------- expert-grouped activation kernel (R2-proven bf16 math, no l2) ------
__global__ __launch_bounds__(256) void act_v2b(const u16* __restrict__ base13,
                                               const u16* __restrict__ B1b,
                                               const u16* __restrict__ B3b,
                                               const u32* __restrict__ lists,
                                               const int* __restrict__ counts,
                                               const float* __restrict__ rw,
                                               u16* __restrict__ sbuf) {
    const int ft = blockIdx.x;
    const int e  = blockIdx.y;
    const int z  = blockIdx.z;
    const int tid = threadIdx.x;
    const int lane = tid & 63;
    const int wave = tid >> 6;
    const int f_lane = ft * FT + lane * 4;

    u16x8 w1c[8], w3c[8];
    {
        const u16* p1 = B1b + ((size_t)e * F_DIM + f_lane) * 16;
        const u16* p3 = B3b + ((size_t)e * F_DIM + f_lane) * 16;
#pragma unroll
        for (int c = 0; c < 8; ++c) {
            w1c[c] = *(const u16x8*)(p1 + c * 8);
            w3c[c] = *(const u16x8*)(p3 + c * 8);
        }
    }

    const int T = counts[e];
    for (int i = z * 4 + wave; i < T; i += TC * 4) {
        u32 ent = lists[e * N_TOK + i];
        int n = (int)(ent & 0xFFFFu);
        int k = (int)(ent >> 16);
        float wt = rw[n * 2 + k];

        float la1[16], la3[16];
        {
            const u16x8* pl1 = (const u16x8*)(base13 + (size_t)n * BN13 + 11264 + e * 16);
            const u16x8* pl3 = (const u16x8*)(base13 + (size_t)n * BN13 + 11392 + e * 16);
#pragma unroll
            for (int h = 0; h < 2; ++h) {
                u16x8 t1 = pl1[h], t3 = pl3[h];
#pragma unroll
                for (int qq = 0; qq < 8; ++qq) {
                    la1[h * 8 + qq] = LSCALE * bf2f(t1[qq]);
                    la3[h * 8 + qq] = LSCALE * bf2f(t3[qq]);
                }
            }
        }

        ushort4 b1u = *(const ushort4*)(base13 + (size_t)n * BN13 + f_lane);
        ushort4 b3u = *(const ushort4*)(base13 + (size_t)n * BN13 + 5632 + f_lane);
        const u16* b1p = (const u16*)&b1u;
        const u16* b3p = (const u16*)&b3u;

        u16 sv[4];
#pragma unroll
        for (int j = 0; j < 4; ++j) {
            float h1 = bf2f(b1p[j]);
            float h3 = bf2f(b3p[j]);
#pragma unroll
            for (int qq = 0; qq < 8; ++qq) {
                h1 += la1[qq] * bf2f(w1c[2 * j][qq]);
                h3 += la3[qq] * bf2f(w3c[2 * j][qq]);
            }
#pragma unroll
            for (int qq = 0; qq < 8; ++qq) {
                h1 += la1[8 + qq] * bf2f(w1c[2 * j + 1][qq]);
                h3 += la3[8 + qq] * bf2f(w3c[2 * j + 1][qq]);
            }
            float sg = h1 / (1.f + __expf(-h1));
            sv[j] = f2bf(wt * sg * h3);
        }
        *(ushort4*)(sbuf + ((size_t)k * N_TOK + n) * F_DIM + f_lane) = *(ushort4*)sv;
    }
}

// ---------------- combine: smix = sbuf0 + sbuf1 (bf16, weights pre-folded) ----------
__global__ __launch_bounds__(256) void combine_kernel(const u16* __restrict__ sbuf,
                                                      u16* __restrict__ smix) {
    size_t i = ((size_t)blockIdx.x * 256 + threadIdx.x) * 8;
    u16x8 a = *(const u16x8*)(sbuf + i);
    u16x8 b = *(const u16x8*)(sbuf + (size_t)N_TOK * F_DIM + i);
    u16x8 o;
#pragma unroll
    for (int q = 0; q < 8; ++q) o[q] = f2bf(bf2f(a[q]) + bf2f(b[q]));
    *(u16x8*)(smix + i) = o;
}

// ---------------- lora_down_v3: l2 = LSCALE*(sbuf @ A2t), out = l2 @ B2^T (WRITES out)
__global__ __launch_bounds__(256) void lora_down_v3(const u16* __restrict__ sbuf,
                                                    const u16* __restrict__ A2t,
                                                    const int* __restrict__ ridx,
                                                    const float* __restrict__ B2,
                                                    float* __restrict__ out) {
    const int n = blockIdx.x, tid = threadIdx.x;
    __shared__ float part[2][32][16];
    __shared__ float fin[2][16];
    __shared__ int se[2];
    if (tid < 2) se[tid] = ridx[n * 2 + tid];
    __syncthreads();

    {
        const int k = tid >> 7;
        const int tt = tid & 127;
        const int rq = tt & 3;
        const int fc = tt >> 2;
        const int e = se[k];
        const u16* srow = sbuf + ((size_t)k * N_TOK + n) * F_DIM + fc * 176;
        const u16* arow = A2t + ((size_t)e * F_DIM + fc * 176) * 16 + rq * 4;
        float acc0 = 0.f, acc1 = 0.f, acc2 = 0.f, acc3 = 0.f;
#pragma unroll 4
        for (int f = 0; f < 176; ++f) {
            float sv = bf2f(srow[f]);
            ushort4 wr = *(const ushort4*)(arow + (size_t)f * 16);
            acc0 += sv * bf2f(wr.x);
            acc1 += sv * bf2f(wr.y);
            acc2 += sv * bf2f(wr.z);
            acc3 += sv * bf2f(wr.w);
        }
        part[k][fc][rq * 4 + 0] = acc0;
        part[k][fc][rq * 4 + 1] = acc1;
        part[k][fc][rq * 4 + 2] = acc2;
        part[k][fc][rq * 4 + 3] = acc3;
    }
    __syncthreads();
    if (tid < 32) {
        int k = tid >> 4, r = tid & 15;
        float s = 0.f;
#pragma unroll
        for (int fc = 0; fc < 32; ++fc) s += part[k][fc][r];
        fin[k][r] = LSCALE * s;
    }
    __syncthreads();

    float a0[16], a1v[16];
#pragma unroll
    for (int r = 0; r < 16; ++r) { a0[r] = fin[0][r]; a1v[r] = fin[1][r]; }
    const float* B2a = B2 + (size_t)se[0] * D_DIM * R_DIM;
    const float* B2b = B2 + (size_t)se[1] * D_DIM * R_DIM;
    float* orow = out + (size_t)n * D_DIM;
    for (int d = tid; d < D_DIM; d += 256) {
        const float4* pa = (const float4*)(B2a + (size_t)d * 16);
        const float4* pb = (const float4*)(B2b + (size_t)d * 16);
        float acc = 0.f;
#pragma unroll
        for (int q = 0; q < 4; ++q) {
            float4 va = pa[q];
            acc += a0[q * 4] * va.x + a0[q * 4 + 1] * va.y +
                   a0[q * 4 + 2] * va.z + a0[q * 4 + 3] * va.w;
            float4 vb = pb[q];
            acc += a1v[q * 4] * vb.x + a1v[q * 4 + 1] * vb.y +
                   a1v[q * 4 + 2] * vb.z + a1v[q * 4 + 3] * vb.w;
        }
        orow[d] = acc;
    }
}

extern "C" void kernel_launch(void* const* d_in, const int* in_sizes, int n_in,
                              void* d_out, int out_size, void* d_ws, size_t ws_size,
                              hipStream_t stream) {
    const float* x  = (const float*)d_in[0];
    const float* gw = (const float*)d_in[1];
    const float* W1 = (const float*)d_in[2];
    const float* W3 = (const float*)d_in[3];
    const float* W2 = (const float*)d_in[4];
    const float* A1 = (const float*)d_in[5];
    const float* B1 = (const float*)d_in[6];
    const float* A3 = (const float*)d_in[7];
    const float* B3 = (const float*)d_in[8];
    const float* A2 = (const float*)d_in[9];
    const float* B2 = (const float*)d_in[10];
    float* out = (float*)d_out;                          // [N, D]
    float* logits = out + (size_t)N_TOK * D_DIM;         // [N, E]

    char* ws = (char*)d_ws;
    size_t off = 0;
    auto alloc = [&](size_t bytes) { char* p = ws + off; off += (bytes + 255) & ~(size_t)255; return p; };
    u16*   xb    = (u16*)alloc((size_t)N_TOK * D_DIM * 2);
    u16*   W13b  = (u16*)alloc((size_t)BN13 * D_DIM * 2);     // W1 | W3 | A1 | A3 (bf16)
    u16*   W2b   = (u16*)alloc((size_t)D_DIM * F_DIM * 2);
    u16*   base13= (u16*)alloc((size_t)N_TOK * BN13 * 2);     // bf16: base1 | base3 | l13
    int*   ridx  = (int*)alloc((size_t)N_TOK * 2 * 4);
    float* rwt   = (float*)alloc((size_t)N_TOK * 2 * 4);
    u16*   B1b   = (u16*)alloc((size_t)E_NUM * F_DIM * R_DIM * 2);  // bf16
    u16*   B3b   = (u16*)alloc((size_t)E_NUM * F_DIM * R_DIM * 2);  // bf16
    u16*   A2t   = (u16*)alloc((size_t)E_NUM * F_DIM * R_DIM * 2);  // bf16
    int*   counts= (int*)alloc(64);
    u32*   lists = (u32*)alloc((size_t)E_NUM * N_TOK * 4);
    u16*   sbuf  = (u16*)alloc((size_t)2 * N_TOK * F_DIM * 2);      // bf16
    u16*   smixb = (u16*)alloc((size_t)N_TOK * F_DIM * 2);          // bf16
    (void)ws_size; (void)in_sizes; (void)n_in; (void)out_size;

    // one fused conversion launch for all bf16 weights/activations
    cvt_all<<<37760, 256, 0, stream>>>(x, W1, W3, A1, A3, W2, B1, B3,
                                       xb, W13b, W2b, B1b, B3b);
    a2_transpose<<<dim3(F_DIM / 256, E_NUM), 256, 0, stream>>>(A2, A2t);

    router_kernel<<<N_TOK, 256, 0, stream>>>(x, gw, logits, ridx, rwt);
    zero_counts<<<1, 64, 0, stream>>>(counts);
    build_lists<<<N_TOK / 256, 256, 0, stream>>>(ridx, counts, lists);

    // fused GEMM: [base1 | base3 | l13] = x @ [W1;W3;A1;A3]^T  (bf16 out)
    // 256x256 tiles: grid = (1024/256) * (11520/256) = 4*45 = 180 blocks
    gemm256<<<180, 512, 0, stream>>>(xb, W13b, (float*)base13,
                                     BN13, D_DIM, D_DIM, /*mode=*/1, /*ntm=*/4, /*ntn=*/45);

    act_v2b<<<dim3(NT, E_NUM, TC), 256, 0, stream>>>(base13, B1b, B3b,
                                                     lists, counts, rwt, sbuf);

    combine_kernel<<<(N_TOK * F_DIM / 8) / 256, 256, 0, stream>>>(sbuf, smixb);

    // l2 from sbuf + LoRA-down; writes out. Then split-K GEMM atomically adds W2 term.
    lora_down_v3<<<N_TOK, 256, 0, stream>>>(sbuf, A2t, ridx, B2, out);

    // out += smix @ W2^T ; 256x256 tiles, split-K z=8 (kslice = 5632/8 = 704)
    // grid = 4 * (2048/256) * 8 = 256 blocks
    gemm256<<<256, 512, 0, stream>>>(smixb, W2b, out,
                                     D_DIM, F_DIM, /*kslice=*/704, /*mode=*/2, /*ntm=*/4, /*ntn=*/8);
}

// Round 3
// 440.031 us; speedup vs baseline: 1.0597x; 1.0555x over previous
//
#include <hip/hip_runtime.h>

typedef unsigned int u32;
typedef unsigned short u16;

#define N_TOK 1024
#define D_DIM 2048
#define F_DIM 5632
#define E_NUM 8
#define R_DIM 16
#define LSCALE 2.0f
#define FT 256            // f-columns per act block
#define NT (F_DIM / FT)   // 22 F-tiles
#define TC 8              // token chunks per expert
#define BN13 11520        // fused B rows: W1(5632) + W3(5632) + A1(128) + A3(128)

typedef __bf16 bf16x8 __attribute__((ext_vector_type(8)));
typedef float f32x4 __attribute__((ext_vector_type(4)));
typedef u16 u16x8 __attribute__((ext_vector_type(8)));

__device__ inline u16 f2bf(float f) {
    u32 u = __builtin_bit_cast(u32, f);
    u32 r = (u + 0x7fffu + ((u >> 16) & 1u)) >> 16;
    return (u16)r;
}
__device__ inline float bf2f(u16 h) {
    u32 u = ((u32)h) << 16;
    return __builtin_bit_cast(float, u);
}

#define LGKM0() do { asm volatile("s_waitcnt lgkmcnt(0)" ::: "memory"); \
                     __builtin_amdgcn_sched_barrier(0); } while (0)
#define VMC(n)  do { asm volatile("s_waitcnt vmcnt(" #n ")" ::: "memory"); \
                     __builtin_amdgcn_sched_barrier(0); } while (0)

// ---------------- fused fp32 -> bf16 conversion for ALL weight tensors (1 launch) ----
__global__ __launch_bounds__(256) void cvt_all(const float* __restrict__ x,
                                               const float* __restrict__ W1,
                                               const float* __restrict__ W3,
                                               const float* __restrict__ A1,
                                               const float* __restrict__ A3,
                                               const float* __restrict__ W2,
                                               const float* __restrict__ B1,
                                               const float* __restrict__ B3,
                                               u16* __restrict__ xb,
                                               u16* __restrict__ w13,
                                               u16* __restrict__ w2b,
                                               u16* __restrict__ b1b,
                                               u16* __restrict__ b3b) {
    int i = blockIdx.x * 256 + threadIdx.x;
    const float* src;
    u16* dst;
    int off;
    if (i < 524288)       { src = x;  dst = xb;             off = i; }
    else if (i < 3407872) { src = W1; dst = w13;            off = i - 524288; }
    else if (i < 6291456) { src = W3; dst = w13 + 11534336; off = i - 3407872; }
    else if (i < 6356992) { src = A1; dst = w13 + 23068672; off = i - 6291456; }
    else if (i < 6422528) { src = A3; dst = w13 + 23330816; off = i - 6356992; }
    else if (i < 9306112) { src = W2; dst = w2b;            off = i - 6422528; }
    else if (i < 9486336) { src = B1; dst = b1b;            off = i - 9306112; }
    else                  { src = B3; dst = b3b;            off = i - 9486336; }
    float4 v = ((const float4*)src)[off];
    union { u16 h[4]; ushort4 u4; } o;
    o.h[0] = f2bf(v.x); o.h[1] = f2bf(v.y); o.h[2] = f2bf(v.z); o.h[3] = f2bf(v.w);
    ((ushort4*)dst)[off] = o.u4;
}

// ---------------- A2 (E,R,F) fp32 -> A2t (E,F,R) bf16 ----------------
__global__ __launch_bounds__(256) void a2_transpose(const float* __restrict__ A2,
                                                    u16* __restrict__ A2t) {
    int e = blockIdx.y;
    int f = blockIdx.x * 256 + threadIdx.x;
    u16 row[16];
#pragma unroll
    for (int r = 0; r < 16; ++r)
        row[r] = f2bf(A2[((size_t)e * R_DIM + r) * F_DIM + f]);
    u16* dst = A2t + ((size_t)e * F_DIM + f) * 16;
#pragma unroll
    for (int q = 0; q < 2; ++q)
        ((ulonglong2*)dst)[q] = ((ulonglong2*)row)[q];
}

// ---------------- router: logits + softmax + top2 ----------------
__global__ __launch_bounds__(256) void router_kernel(const float* __restrict__ x,
                                                     const float* __restrict__ gw,
                                                     float* __restrict__ logits,
                                                     int* __restrict__ ridx,
                                                     float* __restrict__ rw) {
    int n = blockIdx.x;
    int tid = threadIdx.x;
    float part[E_NUM];
#pragma unroll
    for (int e = 0; e < E_NUM; ++e) part[e] = 0.f;
    const float* xr = x + (size_t)n * D_DIM;
    for (int d = tid; d < D_DIM; d += 256) {
        float xv = xr[d];
#pragma unroll
        for (int e = 0; e < E_NUM; ++e) part[e] += xv * gw[e * D_DIM + d];
    }
    __shared__ float sh[E_NUM][256];
#pragma unroll
    for (int e = 0; e < E_NUM; ++e) sh[e][tid] = part[e];
    __syncthreads();
    for (int off = 128; off > 0; off >>= 1) {
        if (tid < off) {
#pragma unroll
            for (int e = 0; e < E_NUM; ++e) sh[e][tid] += sh[e][tid + off];
        }
        __syncthreads();
    }
    if (tid == 0) {
        float lg[E_NUM], p[E_NUM];
        float mx = -1e30f;
        for (int e = 0; e < E_NUM; ++e) {
            lg[e] = sh[e][0];
            logits[n * E_NUM + e] = lg[e];
            if (lg[e] > mx) mx = lg[e];
        }
        float s = 0.f;
        for (int e = 0; e < E_NUM; ++e) { p[e] = expf(lg[e] - mx); s += p[e]; }
        for (int e = 0; e < E_NUM; ++e) p[e] /= s;
        int i1 = 0;
        for (int e = 1; e < E_NUM; ++e) if (p[e] > p[i1]) i1 = e;
        int i2 = (i1 == 0) ? 1 : 0;
        for (int e = 0; e < E_NUM; ++e) if (e != i1 && p[e] > p[i2]) i2 = e;
        float t = p[i1] + p[i2];
        ridx[n * 2] = i1; ridx[n * 2 + 1] = i2;
        rw[n * 2] = p[i1] / t; rw[n * 2 + 1] = p[i2] / t;
    }
}

// ---------------- expert token-list build ----------------
__global__ __launch_bounds__(64) void zero_counts(int* counts) {
    if (threadIdx.x < E_NUM) counts[threadIdx.x] = 0;
}
__global__ __launch_bounds__(256) void build_lists(const int* __restrict__ ridx,
                                                   int* __restrict__ counts,
                                                   u32* __restrict__ lists) {
    int n = blockIdx.x * 256 + threadIdx.x;
    if (n >= N_TOK) return;
#pragma unroll
    for (int k = 0; k < 2; ++k) {
        int e = ridx[n * 2 + k];
        int slot = atomicAdd(&counts[e], 1);
        lists[e * N_TOK + slot] = (u32)n | ((u32)k << 16);
    }
}

// ---------------- 256x256-tile bf16 MFMA GEMM, 4-phase/K-tile schedule --------------
// C[M,N] = A[M,K] @ B[N,K]^T. 512 threads = 8 waves (2M x 4N), wave owns 128x64.
// T2: LDS as two K-half planes [256 rows][32 cols], XOR swizzle (16B slot ^=
//     (row&8)<<1 elems) applied on the GLOBAL source address (linear LDS dest,
//     rule both-sides-or-neither) and identically on ds_read.
// T3/T4: 4 phases per K-tile; counted vmcnt(4) ONCE per tile (A staged 2 tiles
//     ahead, B 1 tile ahead -> 3 half-tile-pairs in flight), vmcnt(0) only at
//     tile nk-2. T5: setprio around each MFMA cluster.
// vmcnt ledger (per wave, 2 loads per stageHalf):
//   prologue: 12 issued, VMC(4) -> tile0's A+B landed, A(t1) in flight.
//   steady phase d: outstanding = A(t+1)4 + B(t+1)4 + A(t+2)4 = 12; VMC(4)
//   retires 8 oldest = tile t+1 fully landed. Barrier joins all waves.
// mode: 0 = f32 store, 1 = bf16 store, 2 = f32 atomic add (split-K).
__global__ __launch_bounds__(512, 2) void gemm256(const u16* __restrict__ A,
                                                  const u16* __restrict__ B,
                                                  float* __restrict__ C,
                                                  int N, int K, int kslice,
                                                  int mode, int ntm, int ntn) {
    // [mat][buf][ksplane][row*32+col] u16  -> 128 KiB
    __shared__ __align__(16) u16 lds[2][2][2][256 * 32];

    // --- bijective XCD-chunked swizzle ---
    const int nb = gridDim.x;
    const int fb = blockIdx.x;
    const int qq = nb >> 3, rr = nb & 7;
    const int xcd = fb & 7, lo = fb >> 3;
    const int wg = (xcd < rr ? xcd * (qq + 1) : rr * (qq + 1) + (xcd - rr) * qq) + lo;

    const int mt = wg % ntm;
    const int t2 = wg / ntm;
    const int nt = t2 % ntn;
    const int zt = t2 / ntn;

    const int bm0 = mt * 256;
    const int bn0 = nt * 256;
    const int kb = zt * kslice;

    const int tid = threadIdx.x;
    const int lane = tid & 63;
    const int wave = tid >> 6;
    const int quad = lane >> 4;
    const int l16 = lane & 15;
    const int swz = (l16 & 8) << 1;     // elem-offset XOR for ds_read (row&8 == l16&8)
    const int wm = (wave >> 2) * 128;   // 0 or 128
    const int wn = (wave & 3) * 64;     // 0,64,128,192

    f32x4 zero = {0.f, 0.f, 0.f, 0.f};
    f32x4 acc[8][4];
#pragma unroll
    for (int i = 0; i < 8; ++i)
#pragma unroll
        for (int j = 0; j < 4; ++j) acc[i][j] = zero;

    // stage one half-tile (128 rows x 64 cols bf16 of one matrix) = 2 loads/thread
    auto stageHalf = [&](const u16* __restrict__ G, int mat, int buf, int h,
                         int k0, int rowBase) {
#pragma unroll
        for (int j = 0; j < 2; ++j) {
            int seg = wave * 2 + j;         // 0..15
            int plane = seg >> 3;
            int rb = seg & 7;
            int r = h * 128 + rb * 16 + (lane >> 2);
            int slot = lane & 3;
            int gcol = k0 + plane * 32 + ((slot * 8) ^ ((r & 8) << 1));
            const u16* gp = G + (size_t)(rowBase + r) * K + gcol;
            u16* lp = &lds[mat][buf][plane][(h * 128 + rb * 16) * 32] + lane * 8;
            __builtin_amdgcn_global_load_lds((const __attribute__((address_space(1))) u32*)gp,
                                             (__attribute__((address_space(3))) u32*)lp,
                                             16, 0, 0);
        }
    };

    const int nk = kslice >> 6;

    // ---- prologue: A(t0) both halves, B(t0) both halves, A(t1) both halves ----
    stageHalf(A, 0, 0, 0, kb, bm0);
    stageHalf(A, 0, 0, 1, kb, bm0);
    stageHalf(B, 1, 0, 0, kb, bn0);
    stageHalf(B, 1, 0, 1, kb, bn0);
    stageHalf(A, 0, 1, 0, kb + 64, bm0);
    stageHalf(A, 0, 1, 1, kb + 64, bm0);
    VMC(4);                      // tile0 landed; A(t1) (4 loads) still in flight
    __builtin_amdgcn_s_barrier();

    bf16x8 af[8][2];
    for (int t = 0; t < nk; ++t) {
        const int buf = t & 1;
        const int k0 = kb + t * 64;

        // ================= phase a: A-lo + B0 reads; MFMA q(lo,0) =================
        {
            bf16x8 bf[2][2];
#pragma unroll
            for (int mi = 0; mi < 4; ++mi)
#pragma unroll
                for (int ks = 0; ks < 2; ++ks)
                    af[mi][ks] = *(const bf16x8*)&lds[0][buf][ks]
                        [(wm + mi * 16 + l16) * 32 + ((quad * 8) ^ swz)];
#pragma unroll
            for (int ni = 0; ni < 2; ++ni)
#pragma unroll
                for (int ks = 0; ks < 2; ++ks)
                    bf[ni][ks] = *(const bf16x8*)&lds[1][buf][ks]
                        [(wn + ni * 16 + l16) * 32 + ((quad * 8) ^ swz)];
            if (t + 1 < nk) stageHalf(B, 1, buf ^ 1, 0, k0 + 64, bn0);
            __builtin_amdgcn_s_barrier();
            LGKM0();
            __builtin_amdgcn_s_setprio(1);
#pragma unroll
            for (int mi = 0; mi < 4; ++mi)
#pragma unroll
                for (int ni = 0; ni < 2; ++ni)
#pragma unroll
                    for (int ks = 0; ks < 2; ++ks)
                        acc[mi][ni] = __builtin_amdgcn_mfma_f32_16x16x32_bf16(
                            af[mi][ks], bf[ni][ks], acc[mi][ni], 0, 0, 0);
            __builtin_amdgcn_s_setprio(0);
            __builtin_amdgcn_s_barrier();
        }

        // ================= phase b: A-hi + B1 reads; MFMA q(lo,1) =================
        {
            bf16x8 bf[2][2];
#pragma unroll
            for (int mi = 0; mi < 4; ++mi)
#pragma unroll
                for (int ks = 0; ks < 2; ++ks)
                    af[4 + mi][ks] = *(const bf16x8*)&lds[0][buf][ks]
                        [(wm + (4 + mi) * 16 + l16) * 32 + ((quad * 8) ^ swz)];
#pragma unroll
            for (int ni = 0; ni < 2; ++ni)
#pragma unroll
                for (int ks = 0; ks < 2; ++ks)
                    bf[ni][ks] = *(const bf16x8*)&lds[1][buf][ks]
                        [(wn + (2 + ni) * 16 + l16) * 32 + ((quad * 8) ^ swz)];
            if (t + 1 < nk) stageHalf(B, 1, buf ^ 1, 1, k0 + 64, bn0);
            __builtin_amdgcn_s_barrier();
            LGKM0();
            __builtin_amdgcn_s_setprio(1);
#pragma unroll
            for (int mi = 0; mi < 4; ++mi)
#pragma unroll
                for (int ni = 0; ni < 2; ++ni)
#pragma unroll
                    for (int ks = 0; ks < 2; ++ks)
                        acc[mi][2 + ni] = __builtin_amdgcn_mfma_f32_16x16x32_bf16(
                            af[mi][ks], bf[ni][ks], acc[mi][2 + ni], 0, 0, 0);
            __builtin_amdgcn_s_setprio(0);
            __builtin_amdgcn_s_barrier();

            // ================= phase c: no reads; MFMA q(hi,1) ====================
            if (t + 2 < nk) stageHalf(A, 0, buf, 0, k0 + 128, bm0);
            __builtin_amdgcn_s_barrier();
            __builtin_amdgcn_s_setprio(1);
#pragma unroll
            for (int mi = 0; mi < 4; ++mi)
#pragma unroll
                for (int ni = 0; ni < 2; ++ni)
#pragma unroll
                    for (int ks = 0; ks < 2; ++ks)
                        acc[4 + mi][2 + ni] = __builtin_amdgcn_mfma_f32_16x16x32_bf16(
                            af[4 + mi][ks], bf[ni][ks], acc[4 + mi][2 + ni], 0, 0, 0);
            __builtin_amdgcn_s_setprio(0);
            __builtin_amdgcn_s_barrier();
        }

        // ================= phase d: B0 re-read; MFMA q(hi,0); vmcnt ===============
        {
            bf16x8 bf[2][2];
#pragma unroll
            for (int ni = 0; ni < 2; ++ni)
#pragma unroll
                for (int ks = 0; ks < 2; ++ks)
                    bf[ni][ks] = *(const bf16x8*)&lds[1][buf][ks]
                        [(wn + ni * 16 + l16) * 32 + ((quad * 8) ^ swz)];
            if (t + 2 < nk) stageHalf(A, 0, buf, 1, k0 + 128, bm0);
            __builtin_amdgcn_s_barrier();
            LGKM0();
            __builtin_amdgcn_s_setprio(1);
#pragma unroll
            for (int mi = 0; mi < 4; ++mi)
#pragma unroll
                for (int ni = 0; ni < 2; ++ni)
#pragma unroll
                    for (int ks = 0; ks < 2; ++ks)
                        acc[4 + mi][ni] = __builtin_amdgcn_mfma_f32_16x16x32_bf16(
                            af[4 + mi][ks], bf[ni][ks], acc[4 + mi][ni], 0, 0, 0);
            __builtin_amdgcn_s_setprio(0);
            if (t < nk - 2)       { VMC(4); }   // tile t+1 fully landed
            else if (t == nk - 2) { VMC(0); }   // final tile fully landed
            __builtin_amdgcn_s_barrier();
        }
    }

#pragma unroll
    for (int mi = 0; mi < 8; ++mi)
#pragma unroll
        for (int ni = 0; ni < 4; ++ni) {
            int col = bn0 + wn + ni * 16 + l16;
#pragma unroll
            for (int i = 0; i < 4; ++i) {
                int row = bm0 + wm + mi * 16 + quad * 4 + i;
                if (mode == 1) {
                    ((u16*)C)[(size_t)row * N + col] = f2bf(acc[mi][ni][i]);
                } else if (mode == 2) {
                    unsafeAtomicAdd(&C[(size_t)row * N + col], acc[mi][ni][i]);
                } else {
                    C[(size_t)row * N + col] = acc[mi][ni][i];
                }
            }
        }
}

// ---------------- expert-grouped activation kernel ----------------
__global__ __launch_bounds__(256) void act_v2b(const u16* __restrict__ base13,
                                               const u16* __restrict__ B1b,
                                               const u16* __restrict__ B3b,
                                               const u32* __restrict__ lists,
                                               const int* __restrict__ counts,
                                               const float* __restrict__ rw,
                                               u16* __restrict__ sbuf) {
    const int ft = blockIdx.x;
    const int e  = blockIdx.y;
    const int z  = blockIdx.z;
    const int tid = threadIdx.x;
    const int lane = tid & 63;
    const int wave = tid >> 6;
    const int f_lane = ft * FT + lane * 4;

    u16x8 w1c[8], w3c[8];
    {
        const u16* p1 = B1b + ((size_t)e * F_DIM + f_lane) * 16;
        const u16* p3 = B3b + ((size_t)e * F_DIM + f_lane) * 16;
#pragma unroll
        for (int c = 0; c < 8; ++c) {
            w1c[c] = *(const u16x8*)(p1 + c * 8);
            w3c[c] = *(const u16x8*)(p3 + c * 8);
        }
    }

    const int T = counts[e];
    for (int i = z * 4 + wave; i < T; i += TC * 4) {
        u32 ent = lists[e * N_TOK + i];
        int n = (int)(ent & 0xFFFFu);
        int k = (int)(ent >> 16);
        float wt = rw[n * 2 + k];

        float la1[16], la3[16];
        {
            const u16x8* pl1 = (const u16x8*)(base13 + (size_t)n * BN13 + 11264 + e * 16);
            const u16x8* pl3 = (const u16x8*)(base13 + (size_t)n * BN13 + 11392 + e * 16);
#pragma unroll
            for (int h = 0; h < 2; ++h) {
                u16x8 t1 = pl1[h], t3 = pl3[h];
#pragma unroll
                for (int qq = 0; qq < 8; ++qq) {
                    la1[h * 8 + qq] = LSCALE * bf2f(t1[qq]);
                    la3[h * 8 + qq] = LSCALE * bf2f(t3[qq]);
                }
            }
        }

        ushort4 b1u = *(const ushort4*)(base13 + (size_t)n * BN13 + f_lane);
        ushort4 b3u = *(const ushort4*)(base13 + (size_t)n * BN13 + 5632 + f_lane);
        const u16* b1p = (const u16*)&b1u;
        const u16* b3p = (const u16*)&b3u;

        u16 sv[4];
#pragma unroll
        for (int j = 0; j < 4; ++j) {
            float h1 = bf2f(b1p[j]);
            float h3 = bf2f(b3p[j]);
#pragma unroll
            for (int qq = 0; qq < 8; ++qq) {
                h1 += la1[qq] * bf2f(w1c[2 * j][qq]);
                h3 += la3[qq] * bf2f(w3c[2 * j][qq]);
            }
#pragma unroll
            for (int qq = 0; qq < 8; ++qq) {
                h1 += la1[8 + qq] * bf2f(w1c[2 * j + 1][qq]);
                h3 += la3[8 + qq] * bf2f(w3c[2 * j + 1][qq]);
            }
            float sg = h1 / (1.f + __expf(-h1));
            sv[j] = f2bf(wt * sg * h3);
        }
        *(ushort4*)(sbuf + ((size_t)k * N_TOK + n) * F_DIM + f_lane) = *(ushort4*)sv;
    }
}

// ---------------- combine: smix = sbuf0 + sbuf1 ----------------
__global__ __launch_bounds__(256) void combine_kernel(const u16* __restrict__ sbuf,
                                                      u16* __restrict__ smix) {
    size_t i = ((size_t)blockIdx.x * 256 + threadIdx.x) * 8;
    u16x8 a = *(const u16x8*)(sbuf + i);
    u16x8 b = *(const u16x8*)(sbuf + (size_t)N_TOK * F_DIM + i);
    u16x8 o;
#pragma unroll
    for (int q = 0; q < 8; ++q) o[q] = f2bf(bf2f(a[q]) + bf2f(b[q]));
    *(u16x8*)(smix + i) = o;
}

// ---------------- lora_down_v3 ----------------
__global__ __launch_bounds__(256) void lora_down_v3(const u16* __restrict__ sbuf,
                                                    const u16* __restrict__ A2t,
                                                    const int* __restrict__ ridx,
                                                    const float* __restrict__ B2,
                                                    float* __restrict__ out) {
    const int n = blockIdx.x, tid = threadIdx.x;
    __shared__ float part[2][32][16];
    __shared__ float fin[2][16];
    __shared__ int se[2];
    if (tid < 2) se[tid] = ridx[n * 2 + tid];
    __syncthreads();

    {
        const int k = tid >> 7;
        const int tt = tid & 127;
        const int rq = tt & 3;
        const int fc = tt >> 2;
        const int e = se[k];
        const u16* srow = sbuf + ((size_t)k * N_TOK + n) * F_DIM + fc * 176;
        const u16* arow = A2t + ((size_t)e * F_DIM + fc * 176) * 16 + rq * 4;
        float acc0 = 0.f, acc1 = 0.f, acc2 = 0.f, acc3 = 0.f;
#pragma unroll 4
        for (int f = 0; f < 176; ++f) {
            float sv = bf2f(srow[f]);
            ushort4 wr = *(const ushort4*)(arow + (size_t)f * 16);
            acc0 += sv * bf2f(wr.x);
            acc1 += sv * bf2f(wr.y);
            acc2 += sv * bf2f(wr.z);
            acc3 += sv * bf2f(wr.w);
        }
        part[k][fc][rq * 4 + 0] = acc0;
        part[k][fc][rq * 4 + 1] = acc1;
        part[k][fc][rq * 4 + 2] = acc2;
        part[k][fc][rq * 4 + 3] = acc3;
    }
    __syncthreads();
    if (tid < 32) {
        int k = tid >> 4, r = tid & 15;
        float s = 0.f;
#pragma unroll
        for (int fc = 0; fc < 32; ++fc) s += part[k][fc][r];
        fin[k][r] = LSCALE * s;
    }
    __syncthreads();

    float a0[16], a1v[16];
#pragma unroll
    for (int r = 0; r < 16; ++r) { a0[r] = fin[0][r]; a1v[r] = fin[1][r]; }
    const float* B2a = B2 + (size_t)se[0] * D_DIM * R_DIM;
    const float* B2b = B2 + (size_t)se[1] * D_DIM * R_DIM;
    float* orow = out + (size_t)n * D_DIM;
    for (int d = tid; d < D_DIM; d += 256) {
        const float4* pa = (const float4*)(B2a + (size_t)d * 16);
        const float4* pb = (const float4*)(B2b + (size_t)d * 16);
        float acc = 0.f;
#pragma unroll
        for (int q = 0; q < 4; ++q) {
            float4 va = pa[q];
            acc += a0[q * 4] * va.x + a0[q * 4 + 1] * va.y +
                   a0[q * 4 + 2] * va.z + a0[q * 4 + 3] * va.w;
            float4 vb = pb[q];
            acc += a1v[q * 4] * vb.x + a1v[q * 4 + 1] * vb.y +
                   a1v[q * 4 + 2] * vb.z + a1v[q * 4 + 3] * vb.w;
        }
        orow[d] = acc;
    }
}

extern "C" void kernel_launch(void* const* d_in, const int* in_sizes, int n_in,
                              void* d_out, int out_size, void* d_ws, size_t ws_size,
                              hipStream_t stream) {
    const float* x  = (const float*)d_in[0];
    const float* gw = (const float*)d_in[1];
    const float* W1 = (const float*)d_in[2];
    const float* W3 = (const float*)d_in[3];
    const float* W2 = (const float*)d_in[4];
    const float* A1 = (const float*)d_in[5];
    const float* B1 = (const float*)d_in[6];
    const float* A3 = (const float*)d_in[7];
    const float* B3 = (const float*)d_in[8];
    const float* A2 = (const float*)d_in[9];
    const float* B2 = (const float*)d_in[10];
    float* out = (float*)d_out;                          // [N, D]
    float* logits = out + (size_t)N_TOK * D_DIM;         // [N, E]

    char* ws = (char*)d_ws;
    size_t off = 0;
    auto alloc = [&](size_t bytes) { char* p = ws + off; off += (bytes + 255) & ~(size_t)255; return p; };
    u16*   xb    = (u16*)alloc((size_t)N_TOK * D_DIM * 2);
    u16*   W13b  = (u16*)alloc((size_t)BN13 * D_DIM * 2);     // W1 | W3 | A1 | A3 (bf16)
    u16*   W2b   = (u16*)alloc((size_t)D_DIM * F_DIM * 2);
    u16*   base13= (u16*)alloc((size_t)N_TOK * BN13 * 2);     // bf16: base1 | base3 | l13
    int*   ridx  = (int*)alloc((size_t)N_TOK * 2 * 4);
    float* rwt   = (float*)alloc((size_t)N_TOK * 2 * 4);
    u16*   B1b   = (u16*)alloc((size_t)E_NUM * F_DIM * R_DIM * 2);  // bf16
    u16*   B3b   = (u16*)alloc((size_t)E_NUM * F_DIM * R_DIM * 2);  // bf16
    u16*   A2t   = (u16*)alloc((size_t)E_NUM * F_DIM * R_DIM * 2);  // bf16
    int*   counts= (int*)alloc(64);
    u32*   lists = (u32*)alloc((size_t)E_NUM * N_TOK * 4);
    u16*   sbuf  = (u16*)alloc((size_t)2 * N_TOK * F_DIM * 2);      // bf16
    u16*   smixb = (u16*)alloc((size_t)N_TOK * F_DIM * 2);          // bf16
    (void)ws_size; (void)in_sizes; (void)n_in; (void)out_size;

    cvt_all<<<37760, 256, 0, stream>>>(x, W1, W3, A1, A3, W2, B1, B3,
                                       xb, W13b, W2b, B1b, B3b);
    a2_transpose<<<dim3(F_DIM / 256, E_NUM), 256, 0, stream>>>(A2, A2t);

    router_kernel<<<N_TOK, 256, 0, stream>>>(x, gw, logits, ridx, rwt);
    zero_counts<<<1, 64, 0, stream>>>(counts);
    build_lists<<<N_TOK / 256, 256, 0, stream>>>(ridx, counts, lists);

    // fused GEMM: [base1 | base3 | l13] = x @ [W1;W3;A1;A3]^T (bf16 out)
    // grid = (1024/256) * (11520/256) = 180, nk = 32
    gemm256<<<180, 512, 0, stream>>>(xb, W13b, (float*)base13,
                                     BN13, D_DIM, D_DIM, /*mode=*/1, /*ntm=*/4, /*ntn=*/45);

    act_v2b<<<dim3(NT, E_NUM, TC), 256, 0, stream>>>(base13, B1b, B3b,
                                                     lists, counts, rwt, sbuf);

    combine_kernel<<<(N_TOK * F_DIM / 8) / 256, 256, 0, stream>>>(sbuf, smixb);

    lora_down_v3<<<N_TOK, 256, 0, stream>>>(sbuf, A2t, ridx, B2, out);

    // out += smix @ W2^T ; split-K z=8 (kslice = 704, nk = 11), grid = 4*8*8 = 256
    gemm256<<<256, 512, 0, stream>>>(smixb, W2b, out,
                                     D_DIM, F_DIM, /*kslice=*/704, /*mode=*/2, /*ntm=*/4, /*ntn=*/8);
}

// Round 4
// 404.496 us; speedup vs baseline: 1.1528x; 1.0879x over previous
//
#include <hip/hip_runtime.h>

typedef unsigned int u32;
typedef unsigned short u16;

#define N_TOK 1024
#define D_DIM 2048
#define F_DIM 5632
#define E_NUM 8
#define R_DIM 16
#define LSCALE 2.0f
#define FT 256            // f-columns per act block
#define NT (F_DIM / FT)   // 22 F-tiles
#define TC 8              // token chunks per expert
#define BN13 11520        // fused B rows: W1(5632) + W3(5632) + A1(128) + A3(128)
#define ZSPLIT 8          // split-K factor for the W2 GEMM

typedef __bf16 bf16x8 __attribute__((ext_vector_type(8)));
typedef float f32x4 __attribute__((ext_vector_type(4)));
typedef u16 u16x8 __attribute__((ext_vector_type(8)));

__device__ inline u16 f2bf(float f) {
    u32 u = __builtin_bit_cast(u32, f);
    u32 r = (u + 0x7fffu + ((u >> 16) & 1u)) >> 16;
    return (u16)r;
}
__device__ inline float bf2f(u16 h) {
    u32 u = ((u32)h) << 16;
    return __builtin_bit_cast(float, u);
}

#define LGKM0() do { asm volatile("s_waitcnt lgkmcnt(0)" ::: "memory"); \
                     __builtin_amdgcn_sched_barrier(0); } while (0)
#define VMC(n)  do { asm volatile("s_waitcnt vmcnt(" #n ")" ::: "memory"); \
                     __builtin_amdgcn_sched_barrier(0); } while (0)

// ---------------- fused fp32 -> bf16 conversion for ALL weight tensors (1 launch) ----
__global__ __launch_bounds__(256) void cvt_all(const float* __restrict__ x,
                                               const float* __restrict__ W1,
                                               const float* __restrict__ W3,
                                               const float* __restrict__ A1,
                                               const float* __restrict__ A3,
                                               const float* __restrict__ W2,
                                               const float* __restrict__ B1,
                                               const float* __restrict__ B3,
                                               u16* __restrict__ xb,
                                               u16* __restrict__ w13,
                                               u16* __restrict__ w2b,
                                               u16* __restrict__ b1b,
                                               u16* __restrict__ b3b) {
    int i = blockIdx.x * 256 + threadIdx.x;
    const float* src;
    u16* dst;
    int off;
    if (i < 524288)       { src = x;  dst = xb;             off = i; }
    else if (i < 3407872) { src = W1; dst = w13;            off = i - 524288; }
    else if (i < 6291456) { src = W3; dst = w13 + 11534336; off = i - 3407872; }
    else if (i < 6356992) { src = A1; dst = w13 + 23068672; off = i - 6291456; }
    else if (i < 6422528) { src = A3; dst = w13 + 23330816; off = i - 6356992; }
    else if (i < 9306112) { src = W2; dst = w2b;            off = i - 6422528; }
    else if (i < 9486336) { src = B1; dst = b1b;            off = i - 9306112; }
    else                  { src = B3; dst = b3b;            off = i - 9486336; }
    float4 v = ((const float4*)src)[off];
    union { u16 h[4]; ushort4 u4; } o;
    o.h[0] = f2bf(v.x); o.h[1] = f2bf(v.y); o.h[2] = f2bf(v.z); o.h[3] = f2bf(v.w);
    ((ushort4*)dst)[off] = o.u4;
}

// ---------------- A2 (E,R,F) fp32 -> A2t (E,F,R) bf16 ----------------
__global__ __launch_bounds__(256) void a2_transpose(const float* __restrict__ A2,
                                                    u16* __restrict__ A2t) {
    int e = blockIdx.y;
    int f = blockIdx.x * 256 + threadIdx.x;
    u16 row[16];
#pragma unroll
    for (int r = 0; r < 16; ++r)
        row[r] = f2bf(A2[((size_t)e * R_DIM + r) * F_DIM + f]);
    u16* dst = A2t + ((size_t)e * F_DIM + f) * 16;
#pragma unroll
    for (int q = 0; q < 2; ++q)
        ((ulonglong2*)dst)[q] = ((ulonglong2*)row)[q];
}

// ---------------- router: logits + softmax + top2 ----------------
__global__ __launch_bounds__(256) void router_kernel(const float* __restrict__ x,
                                                     const float* __restrict__ gw,
                                                     float* __restrict__ logits,
                                                     int* __restrict__ ridx,
                                                     float* __restrict__ rw) {
    int n = blockIdx.x;
    int tid = threadIdx.x;
    float part[E_NUM];
#pragma unroll
    for (int e = 0; e < E_NUM; ++e) part[e] = 0.f;
    const float* xr = x + (size_t)n * D_DIM;
    for (int d = tid; d < D_DIM; d += 256) {
        float xv = xr[d];
#pragma unroll
        for (int e = 0; e < E_NUM; ++e) part[e] += xv * gw[e * D_DIM + d];
    }
    __shared__ float sh[E_NUM][256];
#pragma unroll
    for (int e = 0; e < E_NUM; ++e) sh[e][tid] = part[e];
    __syncthreads();
    for (int off = 128; off > 0; off >>= 1) {
        if (tid < off) {
#pragma unroll
            for (int e = 0; e < E_NUM; ++e) sh[e][tid] += sh[e][tid + off];
        }
        __syncthreads();
    }
    if (tid == 0) {
        float lg[E_NUM], p[E_NUM];
        float mx = -1e30f;
        for (int e = 0; e < E_NUM; ++e) {
            lg[e] = sh[e][0];
            logits[n * E_NUM + e] = lg[e];
            if (lg[e] > mx) mx = lg[e];
        }
        float s = 0.f;
        for (int e = 0; e < E_NUM; ++e) { p[e] = expf(lg[e] - mx); s += p[e]; }
        for (int e = 0; e < E_NUM; ++e) p[e] /= s;
        int i1 = 0;
        for (int e = 1; e < E_NUM; ++e) if (p[e] > p[i1]) i1 = e;
        int i2 = (i1 == 0) ? 1 : 0;
        for (int e = 0; e < E_NUM; ++e) if (e != i1 && p[e] > p[i2]) i2 = e;
        float t = p[i1] + p[i2];
        ridx[n * 2] = i1; ridx[n * 2 + 1] = i2;
        rw[n * 2] = p[i1] / t; rw[n * 2 + 1] = p[i2] / t;
    }
}

// ---------------- expert token-list build ----------------
__global__ __launch_bounds__(64) void zero_counts(int* counts) {
    if (threadIdx.x < E_NUM) counts[threadIdx.x] = 0;
}
__global__ __launch_bounds__(256) void build_lists(const int* __restrict__ ridx,
                                                   int* __restrict__ counts,
                                                   u32* __restrict__ lists) {
    int n = blockIdx.x * 256 + threadIdx.x;
    if (n >= N_TOK) return;
#pragma unroll
    for (int k = 0; k < 2; ++k) {
        int e = ridx[n * 2 + k];
        int slot = atomicAdd(&counts[e], 1);
        lists[e * N_TOK + slot] = (u32)n | ((u32)k << 16);
    }
}

// ---------------- 256x256-tile bf16 MFMA GEMM, 4-phase/K-tile schedule --------------
// C[M,N] = A[M,K] @ B[N,K]^T. 512 threads = 8 waves (2M x 4N), wave owns 128x64.
// T2 swizzle (bank-conflict-free, verified R3: SQ_LDS_BANK_CONFLICT = 0),
// T3/T4 counted vmcnt(4) once per K-tile, T5 setprio. See R3 notes.
// mode: 0 = f32 store to private split-K partial slab (C + zt*ntm*256*N),
//       1 = bf16 store (zt must be 0).
__global__ __launch_bounds__(512, 2) void gemm256(const u16* __restrict__ A,
                                                  const u16* __restrict__ B,
                                                  float* __restrict__ C,
                                                  int N, int K, int kslice,
                                                  int mode, int ntm, int ntn) {
    // [mat][buf][ksplane][row*32+col] u16  -> 128 KiB
    __shared__ __align__(16) u16 lds[2][2][2][256 * 32];

    // --- bijective XCD-chunked swizzle ---
    const int nb = gridDim.x;
    const int fb = blockIdx.x;
    const int qq = nb >> 3, rr = nb & 7;
    const int xcd = fb & 7, lo = fb >> 3;
    const int wg = (xcd < rr ? xcd * (qq + 1) : rr * (qq + 1) + (xcd - rr) * qq) + lo;

    const int mt = wg % ntm;
    const int t2 = wg / ntm;
    const int nt = t2 % ntn;
    const int zt = t2 / ntn;

    const int bm0 = mt * 256;
    const int bn0 = nt * 256;
    const int kb = zt * kslice;

    const int tid = threadIdx.x;
    const int lane = tid & 63;
    const int wave = tid >> 6;
    const int quad = lane >> 4;
    const int l16 = lane & 15;
    const int swz = (l16 & 8) << 1;     // elem-offset XOR for ds_read (row&8 == l16&8)
    const int wm = (wave >> 2) * 128;   // 0 or 128
    const int wn = (wave & 3) * 64;     // 0,64,128,192

    f32x4 zero = {0.f, 0.f, 0.f, 0.f};
    f32x4 acc[8][4];
#pragma unroll
    for (int i = 0; i < 8; ++i)
#pragma unroll
        for (int j = 0; j < 4; ++j) acc[i][j] = zero;

    // stage one half-tile (128 rows x 64 cols bf16 of one matrix) = 2 loads/thread
    auto stageHalf = [&](const u16* __restrict__ G, int mat, int buf, int h,
                         int k0, int rowBase) {
#pragma unroll
        for (int j = 0; j < 2; ++j) {
            int seg = wave * 2 + j;         // 0..15
            int plane = seg >> 3;
            int rb = seg & 7;
            int r = h * 128 + rb * 16 + (lane >> 2);
            int slot = lane & 3;
            int gcol = k0 + plane * 32 + ((slot * 8) ^ ((r & 8) << 1));
            const u16* gp = G + (size_t)(rowBase + r) * K + gcol;
            u16* lp = &lds[mat][buf][plane][(h * 128 + rb * 16) * 32] + lane * 8;
            __builtin_amdgcn_global_load_lds((const __attribute__((address_space(1))) u32*)gp,
                                             (__attribute__((address_space(3))) u32*)lp,
                                             16, 0, 0);
        }
    };

    const int nk = kslice >> 6;

    // ---- prologue: A(t0) both halves, B(t0) both halves, A(t1) both halves ----
    stageHalf(A, 0, 0, 0, kb, bm0);
    stageHalf(A, 0, 0, 1, kb, bm0);
    stageHalf(B, 1, 0, 0, kb, bn0);
    stageHalf(B, 1, 0, 1, kb, bn0);
    stageHalf(A, 0, 1, 0, kb + 64, bm0);
    stageHalf(A, 0, 1, 1, kb + 64, bm0);
    VMC(4);                      // tile0 landed; A(t1) (4 loads) still in flight
    __builtin_amdgcn_s_barrier();

    bf16x8 af[8][2];
    for (int t = 0; t < nk; ++t) {
        const int buf = t & 1;
        const int k0 = kb + t * 64;

        // ================= phase a: A-lo + B0 reads; MFMA q(lo,0) =================
        {
            bf16x8 bf[2][2];
#pragma unroll
            for (int mi = 0; mi < 4; ++mi)
#pragma unroll
                for (int ks = 0; ks < 2; ++ks)
                    af[mi][ks] = *(const bf16x8*)&lds[0][buf][ks]
                        [(wm + mi * 16 + l16) * 32 + ((quad * 8) ^ swz)];
#pragma unroll
            for (int ni = 0; ni < 2; ++ni)
#pragma unroll
                for (int ks = 0; ks < 2; ++ks)
                    bf[ni][ks] = *(const bf16x8*)&lds[1][buf][ks]
                        [(wn + ni * 16 + l16) * 32 + ((quad * 8) ^ swz)];
            if (t + 1 < nk) stageHalf(B, 1, buf ^ 1, 0, k0 + 64, bn0);
            __builtin_amdgcn_s_barrier();
            LGKM0();
            __builtin_amdgcn_s_setprio(1);
#pragma unroll
            for (int mi = 0; mi < 4; ++mi)
#pragma unroll
                for (int ni = 0; ni < 2; ++ni)
#pragma unroll
                    for (int ks = 0; ks < 2; ++ks)
                        acc[mi][ni] = __builtin_amdgcn_mfma_f32_16x16x32_bf16(
                            af[mi][ks], bf[ni][ks], acc[mi][ni], 0, 0, 0);
            __builtin_amdgcn_s_setprio(0);
            __builtin_amdgcn_s_barrier();
        }

        // ================= phase b: A-hi + B1 reads; MFMA q(lo,1) =================
        {
            bf16x8 bf[2][2];
#pragma unroll
            for (int mi = 0; mi < 4; ++mi)
#pragma unroll
                for (int ks = 0; ks < 2; ++ks)
                    af[4 + mi][ks] = *(const bf16x8*)&lds[0][buf][ks]
                        [(wm + (4 + mi) * 16 + l16) * 32 + ((quad * 8) ^ swz)];
#pragma unroll
            for (int ni = 0; ni < 2; ++ni)
#pragma unroll
                for (int ks = 0; ks < 2; ++ks)
                    bf[ni][ks] = *(const bf16x8*)&lds[1][buf][ks]
                        [(wn + (2 + ni) * 16 + l16) * 32 + ((quad * 8) ^ swz)];
            if (t + 1 < nk) stageHalf(B, 1, buf ^ 1, 1, k0 + 64, bn0);
            __builtin_amdgcn_s_barrier();
            LGKM0();
            __builtin_amdgcn_s_setprio(1);
#pragma unroll
            for (int mi = 0; mi < 4; ++mi)
#pragma unroll
                for (int ni = 0; ni < 2; ++ni)
#pragma unroll
                    for (int ks = 0; ks < 2; ++ks)
                        acc[mi][2 + ni] = __builtin_amdgcn_mfma_f32_16x16x32_bf16(
                            af[mi][ks], bf[ni][ks], acc[mi][2 + ni], 0, 0, 0);
            __builtin_amdgcn_s_setprio(0);
            __builtin_amdgcn_s_barrier();

            // ================= phase c: no reads; MFMA q(hi,1) ====================
            if (t + 2 < nk) stageHalf(A, 0, buf, 0, k0 + 128, bm0);
            __builtin_amdgcn_s_barrier();
            __builtin_amdgcn_s_setprio(1);
#pragma unroll
            for (int mi = 0; mi < 4; ++mi)
#pragma unroll
                for (int ni = 0; ni < 2; ++ni)
#pragma unroll
                    for (int ks = 0; ks < 2; ++ks)
                        acc[4 + mi][2 + ni] = __builtin_amdgcn_mfma_f32_16x16x32_bf16(
                            af[4 + mi][ks], bf[ni][ks], acc[4 + mi][2 + ni], 0, 0, 0);
            __builtin_amdgcn_s_setprio(0);
            __builtin_amdgcn_s_barrier();
        }

        // ================= phase d: B0 re-read; MFMA q(hi,0); vmcnt ===============
        {
            bf16x8 bf[2][2];
#pragma unroll
            for (int ni = 0; ni < 2; ++ni)
#pragma unroll
                for (int ks = 0; ks < 2; ++ks)
                    bf[ni][ks] = *(const bf16x8*)&lds[1][buf][ks]
                        [(wn + ni * 16 + l16) * 32 + ((quad * 8) ^ swz)];
            if (t + 2 < nk) stageHalf(A, 0, buf, 1, k0 + 128, bm0);
            __builtin_amdgcn_s_barrier();
            LGKM0();
            __builtin_amdgcn_s_setprio(1);
#pragma unroll
            for (int mi = 0; mi < 4; ++mi)
#pragma unroll
                for (int ni = 0; ni < 2; ++ni)
#pragma unroll
                    for (int ks = 0; ks < 2; ++ks)
                        acc[4 + mi][ni] = __builtin_amdgcn_mfma_f32_16x16x32_bf16(
                            af[4 + mi][ks], bf[ni][ks], acc[4 + mi][ni], 0, 0, 0);
            __builtin_amdgcn_s_setprio(0);
            if (t < nk - 2)       { VMC(4); }   // tile t+1 fully landed
            else if (t == nk - 2) { VMC(0); }   // final tile fully landed
            __builtin_amdgcn_s_barrier();
        }
    }

    // epilogue: mode 0 -> private f32 partial slab (no atomics); mode 1 -> bf16
    float* Cz = C + (size_t)zt * ntm * 256 * N;
#pragma unroll
    for (int mi = 0; mi < 8; ++mi)
#pragma unroll
        for (int ni = 0; ni < 4; ++ni) {
            int col = bn0 + wn + ni * 16 + l16;
#pragma unroll
            for (int i = 0; i < 4; ++i) {
                int row = bm0 + wm + mi * 16 + quad * 4 + i;
                if (mode == 1) {
                    ((u16*)C)[(size_t)row * N + col] = f2bf(acc[mi][ni][i]);
                } else {
                    Cz[(size_t)row * N + col] = acc[mi][ni][i];
                }
            }
        }
}

// ---------------- expert-grouped activation kernel ----------------
__global__ __launch_bounds__(256) void act_v2b(const u16* __restrict__ base13,
                                               const u16* __restrict__ B1b,
                                               const u16* __restrict__ B3b,
                                               const u32* __restrict__ lists,
                                               const int* __restrict__ counts,
                                               const float* __restrict__ rw,
                                               u16* __restrict__ sbuf) {
    const int ft = blockIdx.x;
    const int e  = blockIdx.y;
    const int z  = blockIdx.z;
    const int tid = threadIdx.x;
    const int lane = tid & 63;
    const int wave = tid >> 6;
    const int f_lane = ft * FT + lane * 4;

    u16x8 w1c[8], w3c[8];
    {
        const u16* p1 = B1b + ((size_t)e * F_DIM + f_lane) * 16;
        const u16* p3 = B3b + ((size_t)e * F_DIM + f_lane) * 16;
#pragma unroll
        for (int c = 0; c < 8; ++c) {
            w1c[c] = *(const u16x8*)(p1 + c * 8);
            w3c[c] = *(const u16x8*)(p3 + c * 8);
        }
    }

    const int T = counts[e];
    for (int i = z * 4 + wave; i < T; i += TC * 4) {
        u32 ent = lists[e * N_TOK + i];
        int n = (int)(ent & 0xFFFFu);
        int k = (int)(ent >> 16);
        float wt = rw[n * 2 + k];

        float la1[16], la3[16];
        {
            const u16x8* pl1 = (const u16x8*)(base13 + (size_t)n * BN13 + 11264 + e * 16);
            const u16x8* pl3 = (const u16x8*)(base13 + (size_t)n * BN13 + 11392 + e * 16);
#pragma unroll
            for (int h = 0; h < 2; ++h) {
                u16x8 t1 = pl1[h], t3 = pl3[h];
#pragma unroll
                for (int qq = 0; qq < 8; ++qq) {
                    la1[h * 8 + qq] = LSCALE * bf2f(t1[qq]);
                    la3[h * 8 + qq] = LSCALE * bf2f(t3[qq]);
                }
            }
        }

        ushort4 b1u = *(const ushort4*)(base13 + (size_t)n * BN13 + f_lane);
        ushort4 b3u = *(const ushort4*)(base13 + (size_t)n * BN13 + 5632 + f_lane);
        const u16* b1p = (const u16*)&b1u;
        const u16* b3p = (const u16*)&b3u;

        u16 sv[4];
#pragma unroll
        for (int j = 0; j < 4; ++j) {
            float h1 = bf2f(b1p[j]);
            float h3 = bf2f(b3p[j]);
#pragma unroll
            for (int qq = 0; qq < 8; ++qq) {
                h1 += la1[qq] * bf2f(w1c[2 * j][qq]);
                h3 += la3[qq] * bf2f(w3c[2 * j][qq]);
            }
#pragma unroll
            for (int qq = 0; qq < 8; ++qq) {
                h1 += la1[8 + qq] * bf2f(w1c[2 * j + 1][qq]);
                h3 += la3[8 + qq] * bf2f(w3c[2 * j + 1][qq]);
            }
            float sg = h1 / (1.f + __expf(-h1));
            sv[j] = f2bf(wt * sg * h3);
        }
        *(ushort4*)(sbuf + ((size_t)k * N_TOK + n) * F_DIM + f_lane) = *(ushort4*)sv;
    }
}

// ---------------- combine: smix = sbuf0 + sbuf1 ----------------
__global__ __launch_bounds__(256) void combine_kernel(const u16* __restrict__ sbuf,
                                                      u16* __restrict__ smix) {
    size_t i = ((size_t)blockIdx.x * 256 + threadIdx.x) * 8;
    u16x8 a = *(const u16x8*)(sbuf + i);
    u16x8 b = *(const u16x8*)(sbuf + (size_t)N_TOK * F_DIM + i);
    u16x8 o;
#pragma unroll
    for (int q = 0; q < 8; ++q) o[q] = f2bf(bf2f(a[q]) + bf2f(b[q]));
    *(u16x8*)(smix + i) = o;
}

// ---------------- lora_down_v4: l2@B2 + sum of split-K partials -> out --------------
__global__ __launch_bounds__(256) void lora_down_v4(const u16* __restrict__ sbuf,
                                                    const u16* __restrict__ A2t,
                                                    const int* __restrict__ ridx,
                                                    const float* __restrict__ B2,
                                                    const float* __restrict__ pbuf,
                                                    float* __restrict__ out) {
    const int n = blockIdx.x, tid = threadIdx.x;
    __shared__ float part[2][32][16];
    __shared__ float fin[2][16];
    __shared__ int se[2];
    if (tid < 2) se[tid] = ridx[n * 2 + tid];
    __syncthreads();

    {
        const int k = tid >> 7;
        const int tt = tid & 127;
        const int rq = tt & 3;
        const int fc = tt >> 2;
        const int e = se[k];
        const u16* srow = sbuf + ((size_t)k * N_TOK + n) * F_DIM + fc * 176;
        const u16* arow = A2t + ((size_t)e * F_DIM + fc * 176) * 16 + rq * 4;
        float acc0 = 0.f, acc1 = 0.f, acc2 = 0.f, acc3 = 0.f;
#pragma unroll 4
        for (int f = 0; f < 176; ++f) {
            float sv = bf2f(srow[f]);
            ushort4 wr = *(const ushort4*)(arow + (size_t)f * 16);
            acc0 += sv * bf2f(wr.x);
            acc1 += sv * bf2f(wr.y);
            acc2 += sv * bf2f(wr.z);
            acc3 += sv * bf2f(wr.w);
        }
        part[k][fc][rq * 4 + 0] = acc0;
        part[k][fc][rq * 4 + 1] = acc1;
        part[k][fc][rq * 4 + 2] = acc2;
        part[k][fc][rq * 4 + 3] = acc3;
    }
    __syncthreads();
    if (tid < 32) {
        int k = tid >> 4, r = tid & 15;
        float s = 0.f;
#pragma unroll
        for (int fc = 0; fc < 32; ++fc) s += part[k][fc][r];
        fin[k][r] = LSCALE * s;
    }
    __syncthreads();

    float a0[16], a1v[16];
#pragma unroll
    for (int r = 0; r < 16; ++r) { a0[r] = fin[0][r]; a1v[r] = fin[1][r]; }
    const float* B2a = B2 + (size_t)se[0] * D_DIM * R_DIM;
    const float* B2b = B2 + (size_t)se[1] * D_DIM * R_DIM;
    const float* prow = pbuf + (size_t)n * D_DIM;
    float* orow = out + (size_t)n * D_DIM;
    for (int d = tid; d < D_DIM; d += 256) {
        const float4* pa = (const float4*)(B2a + (size_t)d * 16);
        const float4* pb = (const float4*)(B2b + (size_t)d * 16);
        float acc = 0.f;
#pragma unroll
        for (int q = 0; q < 4; ++q) {
            float4 va = pa[q];
            acc += a0[q * 4] * va.x + a0[q * 4 + 1] * va.y +
                   a0[q * 4 + 2] * va.z + a0[q * 4 + 3] * va.w;
            float4 vb = pb[q];
            acc += a1v[q * 4] * vb.x + a1v[q * 4 + 1] * vb.y +
                   a1v[q * 4 + 2] * vb.z + a1v[q * 4 + 3] * vb.w;
        }
        // fold the ZSPLIT split-K partials (L3-resident, written just before)
        float ps = 0.f;
#pragma unroll
        for (int z = 0; z < ZSPLIT; ++z)
            ps += prow[(size_t)z * N_TOK * D_DIM + d];
        orow[d] = acc + ps;
    }
}

extern "C" void kernel_launch(void* const* d_in, const int* in_sizes, int n_in,
                              void* d_out, int out_size, void* d_ws, size_t ws_size,
                              hipStream_t stream) {
    const float* x  = (const float*)d_in[0];
    const float* gw = (const float*)d_in[1];
    const float* W1 = (const float*)d_in[2];
    const float* W3 = (const float*)d_in[3];
    const float* W2 = (const float*)d_in[4];
    const float* A1 = (const float*)d_in[5];
    const float* B1 = (const float*)d_in[6];
    const float* A3 = (const float*)d_in[7];
    const float* B3 = (const float*)d_in[8];
    const float* A2 = (const float*)d_in[9];
    const float* B2 = (const float*)d_in[10];
    float* out = (float*)d_out;                          // [N, D]
    float* logits = out + (size_t)N_TOK * D_DIM;         // [N, E]

    char* ws = (char*)d_ws;
    size_t off = 0;
    auto alloc = [&](size_t bytes) { char* p = ws + off; off += (bytes + 255) & ~(size_t)255; return p; };
    u16*   xb    = (u16*)alloc((size_t)N_TOK * D_DIM * 2);
    u16*   W13b  = (u16*)alloc((size_t)BN13 * D_DIM * 2);     // W1 | W3 | A1 | A3 (bf16)
    u16*   W2b   = (u16*)alloc((size_t)D_DIM * F_DIM * 2);
    u16*   base13= (u16*)alloc((size_t)N_TOK * BN13 * 2);     // bf16: base1 | base3 | l13
    int*   ridx  = (int*)alloc((size_t)N_TOK * 2 * 4);
    float* rwt   = (float*)alloc((size_t)N_TOK * 2 * 4);
    u16*   B1b   = (u16*)alloc((size_t)E_NUM * F_DIM * R_DIM * 2);  // bf16
    u16*   B3b   = (u16*)alloc((size_t)E_NUM * F_DIM * R_DIM * 2);  // bf16
    u16*   A2t   = (u16*)alloc((size_t)E_NUM * F_DIM * R_DIM * 2);  // bf16
    int*   counts= (int*)alloc(64);
    u32*   lists = (u32*)alloc((size_t)E_NUM * N_TOK * 4);
    u16*   sbuf  = (u16*)alloc((size_t)2 * N_TOK * F_DIM * 2);      // bf16
    u16*   smixb = (u16*)alloc((size_t)N_TOK * F_DIM * 2);          // bf16
    float* pbuf  = (float*)alloc((size_t)ZSPLIT * N_TOK * D_DIM * 4); // split-K partials
    (void)ws_size; (void)in_sizes; (void)n_in; (void)out_size;

    cvt_all<<<37760, 256, 0, stream>>>(x, W1, W3, A1, A3, W2, B1, B3,
                                       xb, W13b, W2b, B1b, B3b);
    a2_transpose<<<dim3(F_DIM / 256, E_NUM), 256, 0, stream>>>(A2, A2t);

    router_kernel<<<N_TOK, 256, 0, stream>>>(x, gw, logits, ridx, rwt);
    zero_counts<<<1, 64, 0, stream>>>(counts);
    build_lists<<<N_TOK / 256, 256, 0, stream>>>(ridx, counts, lists);

    // fused GEMM: [base1 | base3 | l13] = x @ [W1;W3;A1;A3]^T (bf16 out)
    // grid = (1024/256) * (11520/256) = 180, nk = 32
    gemm256<<<180, 512, 0, stream>>>(xb, W13b, (float*)base13,
                                     BN13, D_DIM, D_DIM, /*mode=*/1, /*ntm=*/4, /*ntn=*/45);

    act_v2b<<<dim3(NT, E_NUM, TC), 256, 0, stream>>>(base13, B1b, B3b,
                                                     lists, counts, rwt, sbuf);

    combine_kernel<<<(N_TOK * F_DIM / 8) / 256, 256, 0, stream>>>(sbuf, smixb);

    // smix @ W2^T -> split-K partials (NO atomics; private f32 slabs)
    // split-K z=8 (kslice = 704, nk = 11), grid = 4*8*8 = 256
    gemm256<<<256, 512, 0, stream>>>(smixb, W2b, pbuf,
                                     D_DIM, F_DIM, /*kslice=*/704, /*mode=*/0, /*ntm=*/4, /*ntn=*/8);

    // l2@B2 + sum of partials -> out (single writer of out)
    lora_down_v4<<<N_TOK, 256, 0, stream>>>(sbuf, A2t, ridx, B2, pbuf, out);
}

// Round 5
// 401.716 us; speedup vs baseline: 1.1607x; 1.0069x over previous
//
#include <hip/hip_runtime.h>

typedef unsigned int u32;
typedef unsigned short u16;

#define N_TOK 1024
#define D_DIM 2048
#define F_DIM 5632
#define E_NUM 8
#define R_DIM 16
#define LSCALE 2.0f
#define FT 256            // f-columns per act block
#define NT (F_DIM / FT)   // 22 F-tiles
#define TC 8              // token chunks per expert
#define BN13 11520        // fused B rows: W1(5632) + W3(5632) + A1(128) + A3(128)
#define ZSPLIT 8          // split-K factor for the W2 GEMM

typedef __bf16 bf16x8 __attribute__((ext_vector_type(8)));
typedef float f32x4 __attribute__((ext_vector_type(4)));
typedef u16 u16x8 __attribute__((ext_vector_type(8)));

__device__ inline u16 f2bf(float f) {
    u32 u = __builtin_bit_cast(u32, f);
    u32 r = (u + 0x7fffu + ((u >> 16) & 1u)) >> 16;
    return (u16)r;
}
__device__ inline float bf2f(u16 h) {
    u32 u = ((u32)h) << 16;
    return __builtin_bit_cast(float, u);
}

#define LGKM0() do { asm volatile("s_waitcnt lgkmcnt(0)" ::: "memory"); \
                     __builtin_amdgcn_sched_barrier(0); } while (0)
#define VMC(n)  do { asm volatile("s_waitcnt vmcnt(" #n ")" ::: "memory"); \
                     __builtin_amdgcn_sched_barrier(0); } while (0)

// ---------------- fused fp32 -> bf16 conversion for ALL weight tensors (1 launch) ----
__global__ __launch_bounds__(256) void cvt_all(const float* __restrict__ x,
                                               const float* __restrict__ W1,
                                               const float* __restrict__ W3,
                                               const float* __restrict__ A1,
                                               const float* __restrict__ A3,
                                               const float* __restrict__ W2,
                                               const float* __restrict__ B1,
                                               const float* __restrict__ B3,
                                               u16* __restrict__ xb,
                                               u16* __restrict__ w13,
                                               u16* __restrict__ w2b,
                                               u16* __restrict__ b1b,
                                               u16* __restrict__ b3b) {
    int i = blockIdx.x * 256 + threadIdx.x;
    const float* src;
    u16* dst;
    int off;
    if (i < 524288)       { src = x;  dst = xb;             off = i; }
    else if (i < 3407872) { src = W1; dst = w13;            off = i - 524288; }
    else if (i < 6291456) { src = W3; dst = w13 + 11534336; off = i - 3407872; }
    else if (i < 6356992) { src = A1; dst = w13 + 23068672; off = i - 6291456; }
    else if (i < 6422528) { src = A3; dst = w13 + 23330816; off = i - 6356992; }
    else if (i < 9306112) { src = W2; dst = w2b;            off = i - 6422528; }
    else if (i < 9486336) { src = B1; dst = b1b;            off = i - 9306112; }
    else                  { src = B3; dst = b3b;            off = i - 9486336; }
    float4 v = ((const float4*)src)[off];
    union { u16 h[4]; ushort4 u4; } o;
    o.h[0] = f2bf(v.x); o.h[1] = f2bf(v.y); o.h[2] = f2bf(v.z); o.h[3] = f2bf(v.w);
    ((ushort4*)dst)[off] = o.u4;
}

// ---------------- A2 (E,R,F) fp32 -> A2t (E,F,R) bf16 ----------------
__global__ __launch_bounds__(256) void a2_transpose(const float* __restrict__ A2,
                                                    u16* __restrict__ A2t) {
    int e = blockIdx.y;
    int f = blockIdx.x * 256 + threadIdx.x;
    u16 row[16];
#pragma unroll
    for (int r = 0; r < 16; ++r)
        row[r] = f2bf(A2[((size_t)e * R_DIM + r) * F_DIM + f]);
    u16* dst = A2t + ((size_t)e * F_DIM + f) * 16;
#pragma unroll
    for (int q = 0; q < 2; ++q)
        ((ulonglong2*)dst)[q] = ((ulonglong2*)row)[q];
}

// ---------------- router: logits + softmax + top2 ----------------
__global__ __launch_bounds__(256) void router_kernel(const float* __restrict__ x,
                                                     const float* __restrict__ gw,
                                                     float* __restrict__ logits,
                                                     int* __restrict__ ridx,
                                                     float* __restrict__ rw) {
    int n = blockIdx.x;
    int tid = threadIdx.x;
    float part[E_NUM];
#pragma unroll
    for (int e = 0; e < E_NUM; ++e) part[e] = 0.f;
    const float* xr = x + (size_t)n * D_DIM;
    for (int d = tid; d < D_DIM; d += 256) {
        float xv = xr[d];
#pragma unroll
        for (int e = 0; e < E_NUM; ++e) part[e] += xv * gw[e * D_DIM + d];
    }
    __shared__ float sh[E_NUM][256];
#pragma unroll
    for (int e = 0; e < E_NUM; ++e) sh[e][tid] = part[e];
    __syncthreads();
    for (int off = 128; off > 0; off >>= 1) {
        if (tid < off) {
#pragma unroll
            for (int e = 0; e < E_NUM; ++e) sh[e][tid] += sh[e][tid + off];
        }
        __syncthreads();
    }
    if (tid == 0) {
        float lg[E_NUM], p[E_NUM];
        float mx = -1e30f;
        for (int e = 0; e < E_NUM; ++e) {
            lg[e] = sh[e][0];
            logits[n * E_NUM + e] = lg[e];
            if (lg[e] > mx) mx = lg[e];
        }
        float s = 0.f;
        for (int e = 0; e < E_NUM; ++e) { p[e] = expf(lg[e] - mx); s += p[e]; }
        for (int e = 0; e < E_NUM; ++e) p[e] /= s;
        int i1 = 0;
        for (int e = 1; e < E_NUM; ++e) if (p[e] > p[i1]) i1 = e;
        int i2 = (i1 == 0) ? 1 : 0;
        for (int e = 0; e < E_NUM; ++e) if (e != i1 && p[e] > p[i2]) i2 = e;
        float t = p[i1] + p[i2];
        ridx[n * 2] = i1; ridx[n * 2 + 1] = i2;
        rw[n * 2] = p[i1] / t; rw[n * 2 + 1] = p[i2] / t;
    }
}

// ---------------- expert token-list build ----------------
__global__ __launch_bounds__(64) void zero_counts(int* counts) {
    if (threadIdx.x < E_NUM) counts[threadIdx.x] = 0;
}
__global__ __launch_bounds__(256) void build_lists(const int* __restrict__ ridx,
                                                   int* __restrict__ counts,
                                                   u32* __restrict__ lists) {
    int n = blockIdx.x * 256 + threadIdx.x;
    if (n >= N_TOK) return;
#pragma unroll
    for (int k = 0; k < 2; ++k) {
        int e = ridx[n * 2 + k];
        int slot = atomicAdd(&counts[e], 1);
        lists[e * N_TOK + slot] = (u32)n | ((u32)k << 16);
    }
}

// ---------------- 256x256-tile bf16 MFMA GEMM, 4-phase/K-tile schedule --------------
// C[M,N] = A[M,K] @ B[N,K]^T. 512 threads = 8 waves (2M x 4N), wave owns 128x64.
// R4 rework: MINIMAL LDS reads (24 b128/wave/K-tile, was 28), balanced 8,8,4,4:
//   a: read A(mi0-3,ks0)+B(ks0); MFMA mi0-3*ks0; stage A(t+1)h0 (other buf, safe)
//   b: read A(mi4-7,ks0)+B(ks1); MFMA mi4-7*ks0; stage A(t+1)h1
//   c: read A(mi0-3,ks1);        MFMA mi0-3*ks1; stage B(t+2)h0 (B reads done @b)
//   d: read A(mi4-7,ks1);        MFMA mi4-7*ks1; stage B(t+2)h1; counted VMC
// vmcnt ledger (2 loads per stageHalf, per wave): at tile-t start exactly
//   B(t+1):4 in flight. a:+2 b:+2 (A(t+1)) c:+2 d:+2 (B(t+2)) -> 12;
//   VMC(4) retires 8 oldest = B(t+1)+A(t+1) -> tile t+1 landed. Tail:
//   t==nk-2 -> VMC(0). Prologue: A(0),B(0),B(1); VMC(4).
// T2 swizzle (bank-conflict-free, verified R3: SQ_LDS_BANK_CONFLICT = 0).
// mode: 0 = f32 store to private split-K partial slab (C + zt*ntm*256*N),
//       1 = bf16 store (zt must be 0).
__global__ __launch_bounds__(512, 2) void gemm256(const u16* __restrict__ A,
                                                  const u16* __restrict__ B,
                                                  float* __restrict__ C,
                                                  int N, int K, int kslice,
                                                  int mode, int ntm, int ntn) {
    // [mat][buf][ksplane][row*32+col] u16  -> 128 KiB
    __shared__ __align__(16) u16 lds[2][2][2][256 * 32];

    // --- bijective XCD-chunked swizzle ---
    const int nb = gridDim.x;
    const int fb = blockIdx.x;
    const int qq = nb >> 3, rr = nb & 7;
    const int xcd = fb & 7, lo = fb >> 3;
    const int wg = (xcd < rr ? xcd * (qq + 1) : rr * (qq + 1) + (xcd - rr) * qq) + lo;

    const int mt = wg % ntm;
    const int t2 = wg / ntm;
    const int nt = t2 % ntn;
    const int zt = t2 / ntn;

    const int bm0 = mt * 256;
    const int bn0 = nt * 256;
    const int kb = zt * kslice;

    const int tid = threadIdx.x;
    const int lane = tid & 63;
    const int wave = tid >> 6;
    const int quad = lane >> 4;
    const int l16 = lane & 15;
    const int swz = (l16 & 8) << 1;     // elem-offset XOR for ds_read (row&8 == l16&8)
    const int wm = (wave >> 2) * 128;   // 0 or 128
    const int wn = (wave & 3) * 64;     // 0,64,128,192

    f32x4 zero = {0.f, 0.f, 0.f, 0.f};
    f32x4 acc[8][4];
#pragma unroll
    for (int i = 0; i < 8; ++i)
#pragma unroll
        for (int j = 0; j < 4; ++j) acc[i][j] = zero;

    // stage one half-tile (128 rows x 64 cols bf16 of one matrix) = 2 loads/thread
    auto stageHalf = [&](const u16* __restrict__ G, int mat, int buf, int h,
                         int k0, int rowBase) {
#pragma unroll
        for (int j = 0; j < 2; ++j) {
            int seg = wave * 2 + j;         // 0..15
            int plane = seg >> 3;
            int rb = seg & 7;
            int r = h * 128 + rb * 16 + (lane >> 2);
            int slot = lane & 3;
            int gcol = k0 + plane * 32 + ((slot * 8) ^ ((r & 8) << 1));
            const u16* gp = G + (size_t)(rowBase + r) * K + gcol;
            u16* lp = &lds[mat][buf][plane][(h * 128 + rb * 16) * 32] + lane * 8;
            __builtin_amdgcn_global_load_lds((const __attribute__((address_space(1))) u32*)gp,
                                             (__attribute__((address_space(3))) u32*)lp,
                                             16, 0, 0);
        }
    };

    // fragment loaders (swizzled ds_read addresses)
    auto ldA = [&](int buf, int ks, int mi) -> bf16x8 {
        return *(const bf16x8*)&lds[0][buf][ks]
            [(wm + mi * 16 + l16) * 32 + ((quad * 8) ^ swz)];
    };
    auto ldB = [&](int buf, int ks, int ni) -> bf16x8 {
        return *(const bf16x8*)&lds[1][buf][ks]
            [(wn + ni * 16 + l16) * 32 + ((quad * 8) ^ swz)];
    };

    const int nk = kslice >> 6;

    // ---- prologue: A(t0) both halves, B(t0) both halves, B(t1) both halves ----
    stageHalf(A, 0, 0, 0, kb, bm0);
    stageHalf(A, 0, 0, 1, kb, bm0);
    stageHalf(B, 1, 0, 0, kb, bn0);
    stageHalf(B, 1, 0, 1, kb, bn0);
    stageHalf(B, 1, 1, 0, kb + 64, bn0);
    stageHalf(B, 1, 1, 1, kb + 64, bn0);
    VMC(4);                      // tile0 landed; B(t1) (4 loads) still in flight
    __builtin_amdgcn_s_barrier();

    for (int t = 0; t < nk; ++t) {
        const int buf = t & 1;
        const int k0 = kb + t * 64;
        bf16x8 bq0[4], bq1[4];   // B frags ks0 / ks1, live across phases

        // ===== phase a: read A(mi0-3,ks0)+B(ks0); MFMA mi0-3*ks0; stage A(t+1)h0 ====
        {
            bf16x8 av[4];
#pragma unroll
            for (int mi = 0; mi < 4; ++mi) av[mi] = ldA(buf, 0, mi);
#pragma unroll
            for (int ni = 0; ni < 4; ++ni) bq0[ni] = ldB(buf, 0, ni);
            if (t + 1 < nk) stageHalf(A, 0, buf ^ 1, 0, k0 + 64, bm0);
            __builtin_amdgcn_s_barrier();
            LGKM0();
            __builtin_amdgcn_s_setprio(1);
#pragma unroll
            for (int mi = 0; mi < 4; ++mi)
#pragma unroll
                for (int ni = 0; ni < 4; ++ni)
                    acc[mi][ni] = __builtin_amdgcn_mfma_f32_16x16x32_bf16(
                        av[mi], bq0[ni], acc[mi][ni], 0, 0, 0);
            __builtin_amdgcn_s_setprio(0);
            __builtin_amdgcn_s_barrier();
        }

        // ===== phase b: read A(mi4-7,ks0)+B(ks1); MFMA mi4-7*ks0; stage A(t+1)h1 ====
        {
            bf16x8 av[4];
#pragma unroll
            for (int mi = 0; mi < 4; ++mi) av[mi] = ldA(buf, 0, 4 + mi);
#pragma unroll
            for (int ni = 0; ni < 4; ++ni) bq1[ni] = ldB(buf, 1, ni);
            if (t + 1 < nk) stageHalf(A, 0, buf ^ 1, 1, k0 + 64, bm0);
            __builtin_amdgcn_s_barrier();
            LGKM0();
            __builtin_amdgcn_s_setprio(1);
#pragma unroll
            for (int mi = 0; mi < 4; ++mi)
#pragma unroll
                for (int ni = 0; ni < 4; ++ni)
                    acc[4 + mi][ni] = __builtin_amdgcn_mfma_f32_16x16x32_bf16(
                        av[mi], bq0[ni], acc[4 + mi][ni], 0, 0, 0);
            __builtin_amdgcn_s_setprio(0);
            __builtin_amdgcn_s_barrier();
        }

        // ===== phase c: read A(mi0-3,ks1); MFMA mi0-3*ks1; stage B(t+2)h0 ===========
        {
            bf16x8 av[4];
#pragma unroll
            for (int mi = 0; mi < 4; ++mi) av[mi] = ldA(buf, 1, mi);
            if (t + 2 < nk) stageHalf(B, 1, buf, 0, k0 + 128, bn0);
            __builtin_amdgcn_s_barrier();
            LGKM0();
            __builtin_amdgcn_s_setprio(1);
#pragma unroll
            for (int mi = 0; mi < 4; ++mi)
#pragma unroll
                for (int ni = 0; ni < 4; ++ni)
                    acc[mi][ni] = __builtin_amdgcn_mfma_f32_16x16x32_bf16(
                        av[mi], bq1[ni], acc[mi][ni], 0, 0, 0);
            __builtin_amdgcn_s_setprio(0);
            __builtin_amdgcn_s_barrier();
        }

        // ===== phase d: read A(mi4-7,ks1); MFMA mi4-7*ks1; stage B(t+2)h1; VMC ======
        {
            bf16x8 av[4];
#pragma unroll
            for (int mi = 0; mi < 4; ++mi) av[mi] = ldA(buf, 1, 4 + mi);
            if (t + 2 < nk) stageHalf(B, 1, buf, 1, k0 + 128, bn0);
            __builtin_amdgcn_s_barrier();
            LGKM0();
            __builtin_amdgcn_s_setprio(1);
#pragma unroll
            for (int mi = 0; mi < 4; ++mi)
#pragma unroll
                for (int ni = 0; ni < 4; ++ni)
                    acc[4 + mi][ni] = __builtin_amdgcn_mfma_f32_16x16x32_bf16(
                        av[mi], bq1[ni], acc[4 + mi][ni], 0, 0, 0);
            __builtin_amdgcn_s_setprio(0);
            if (t < nk - 2)       { VMC(4); }   // tile t+1 fully landed
            else if (t == nk - 2) { VMC(0); }   // final tile fully landed
            __builtin_amdgcn_s_barrier();
        }
    }

    // epilogue: mode 0 -> private f32 partial slab (no atomics); mode 1 -> bf16
    float* Cz = C + (size_t)zt * ntm * 256 * N;
#pragma unroll
    for (int mi = 0; mi < 8; ++mi)
#pragma unroll
        for (int ni = 0; ni < 4; ++ni) {
            int col = bn0 + wn + ni * 16 + l16;
#pragma unroll
            for (int i = 0; i < 4; ++i) {
                int row = bm0 + wm + mi * 16 + quad * 4 + i;
                if (mode == 1) {
                    ((u16*)C)[(size_t)row * N + col] = f2bf(acc[mi][ni][i]);
                } else {
                    Cz[(size_t)row * N + col] = acc[mi][ni][i];
                }
            }
        }
}

// ---------------- expert-grouped activation kernel ----------------
__global__ __launch_bounds__(256) void act_v2b(const u16* __restrict__ base13,
                                               const u16* __restrict__ B1b,
                                               const u16* __restrict__ B3b,
                                               const u32* __restrict__ lists,
                                               const int* __restrict__ counts,
                                               const float* __restrict__ rw,
                                               u16* __restrict__ sbuf) {
    const int ft = blockIdx.x;
    const int e  = blockIdx.y;
    const int z  = blockIdx.z;
    const int tid = threadIdx.x;
    const int lane = tid & 63;
    const int wave = tid >> 6;
    const int f_lane = ft * FT + lane * 4;

    u16x8 w1c[8], w3c[8];
    {
        const u16* p1 = B1b + ((size_t)e * F_DIM + f_lane) * 16;
        const u16* p3 = B3b + ((size_t)e * F_DIM + f_lane) * 16;
#pragma unroll
        for (int c = 0; c < 8; ++c) {
            w1c[c] = *(const u16x8*)(p1 + c * 8);
            w3c[c] = *(const u16x8*)(p3 + c * 8);
        }
    }

    const int T = counts[e];
    for (int i = z * 4 + wave; i < T; i += TC * 4) {
        u32 ent = lists[e * N_TOK + i];
        int n = (int)(ent & 0xFFFFu);
        int k = (int)(ent >> 16);
        float wt = rw[n * 2 + k];

        float la1[16], la3[16];
        {
            const u16x8* pl1 = (const u16x8*)(base13 + (size_t)n * BN13 + 11264 + e * 16);
            const u16x8* pl3 = (const u16x8*)(base13 + (size_t)n * BN13 + 11392 + e * 16);
#pragma unroll
            for (int h = 0; h < 2; ++h) {
                u16x8 t1 = pl1[h], t3 = pl3[h];
#pragma unroll
                for (int qq = 0; qq < 8; ++qq) {
                    la1[h * 8 + qq] = LSCALE * bf2f(t1[qq]);
                    la3[h * 8 + qq] = LSCALE * bf2f(t3[qq]);
                }
            }
        }

        ushort4 b1u = *(const ushort4*)(base13 + (size_t)n * BN13 + f_lane);
        ushort4 b3u = *(const ushort4*)(base13 + (size_t)n * BN13 + 5632 + f_lane);
        const u16* b1p = (const u16*)&b1u;
        const u16* b3p = (const u16*)&b3u;

        u16 sv[4];
#pragma unroll
        for (int j = 0; j < 4; ++j) {
            float h1 = bf2f(b1p[j]);
            float h3 = bf2f(b3p[j]);
#pragma unroll
            for (int qq = 0; qq < 8; ++qq) {
                h1 += la1[qq] * bf2f(w1c[2 * j][qq]);
                h3 += la3[qq] * bf2f(w3c[2 * j][qq]);
            }
#pragma unroll
            for (int qq = 0; qq < 8; ++qq) {
                h1 += la1[8 + qq] * bf2f(w1c[2 * j + 1][qq]);
                h3 += la3[8 + qq] * bf2f(w3c[2 * j + 1][qq]);
            }
            float sg = h1 / (1.f + __expf(-h1));
            sv[j] = f2bf(wt * sg * h3);
        }
        *(ushort4*)(sbuf + ((size_t)k * N_TOK + n) * F_DIM + f_lane) = *(ushort4*)sv;
    }
}

// ---------------- combine: smix = sbuf0 + sbuf1 ----------------
__global__ __launch_bounds__(256) void combine_kernel(const u16* __restrict__ sbuf,
                                                      u16* __restrict__ smix) {
    size_t i = ((size_t)blockIdx.x * 256 + threadIdx.x) * 8;
    u16x8 a = *(const u16x8*)(sbuf + i);
    u16x8 b = *(const u16x8*)(sbuf + (size_t)N_TOK * F_DIM + i);
    u16x8 o;
#pragma unroll
    for (int q = 0; q < 8; ++q) o[q] = f2bf(bf2f(a[q]) + bf2f(b[q]));
    *(u16x8*)(smix + i) = o;
}

// ---------------- lora_down_v4: l2@B2 + sum of split-K partials -> out --------------
__global__ __launch_bounds__(256) void lora_down_v4(const u16* __restrict__ sbuf,
                                                    const u16* __restrict__ A2t,
                                                    const int* __restrict__ ridx,
                                                    const float* __restrict__ B2,
                                                    const float* __restrict__ pbuf,
                                                    float* __restrict__ out) {
    const int n = blockIdx.x, tid = threadIdx.x;
    __shared__ float part[2][32][16];
    __shared__ float fin[2][16];
    __shared__ int se[2];
    if (tid < 2) se[tid] = ridx[n * 2 + tid];
    __syncthreads();

    {
        const int k = tid >> 7;
        const int tt = tid & 127;
        const int rq = tt & 3;
        const int fc = tt >> 2;
        const int e = se[k];
        const u16* srow = sbuf + ((size_t)k * N_TOK + n) * F_DIM + fc * 176;
        const u16* arow = A2t + ((size_t)e * F_DIM + fc * 176) * 16 + rq * 4;
        float acc0 = 0.f, acc1 = 0.f, acc2 = 0.f, acc3 = 0.f;
#pragma unroll 4
        for (int f = 0; f < 176; ++f) {
            float sv = bf2f(srow[f]);
            ushort4 wr = *(const ushort4*)(arow + (size_t)f * 16);
            acc0 += sv * bf2f(wr.x);
            acc1 += sv * bf2f(wr.y);
            acc2 += sv * bf2f(wr.z);
            acc3 += sv * bf2f(wr.w);
        }
        part[k][fc][rq * 4 + 0] = acc0;
        part[k][fc][rq * 4 + 1] = acc1;
        part[k][fc][rq * 4 + 2] = acc2;
        part[k][fc][rq * 4 + 3] = acc3;
    }
    __syncthreads();
    if (tid < 32) {
        int k = tid >> 4, r = tid & 15;
        float s = 0.f;
#pragma unroll
        for (int fc = 0; fc < 32; ++fc) s += part[k][fc][r];
        fin[k][r] = LSCALE * s;
    }
    __syncthreads();

    float a0[16], a1v[16];
#pragma unroll
    for (int r = 0; r < 16; ++r) { a0[r] = fin[0][r]; a1v[r] = fin[1][r]; }
    const float* B2a = B2 + (size_t)se[0] * D_DIM * R_DIM;
    const float* B2b = B2 + (size_t)se[1] * D_DIM * R_DIM;
    const float* prow = pbuf + (size_t)n * D_DIM;
    float* orow = out + (size_t)n * D_DIM;
    for (int d = tid; d < D_DIM; d += 256) {
        const float4* pa = (const float4*)(B2a + (size_t)d * 16);
        const float4* pb = (const float4*)(B2b + (size_t)d * 16);
        float acc = 0.f;
#pragma unroll
        for (int q = 0; q < 4; ++q) {
            float4 va = pa[q];
            acc += a0[q * 4] * va.x + a0[q * 4 + 1] * va.y +
                   a0[q * 4 + 2] * va.z + a0[q * 4 + 3] * va.w;
            float4 vb = pb[q];
            acc += a1v[q * 4] * vb.x + a1v[q * 4 + 1] * vb.y +
                   a1v[q * 4 + 2] * vb.z + a1v[q * 4 + 3] * vb.w;
        }
        // fold the ZSPLIT split-K partials (L3-resident, written just before)
        float ps = 0.f;
#pragma unroll
        for (int z = 0; z < ZSPLIT; ++z)
            ps += prow[(size_t)z * N_TOK * D_DIM + d];
        orow[d] = acc + ps;
    }
}

extern "C" void kernel_launch(void* const* d_in, const int* in_sizes, int n_in,
                              void* d_out, int out_size, void* d_ws, size_t ws_size,
                              hipStream_t stream) {
    const float* x  = (const float*)d_in[0];
    const float* gw = (const float*)d_in[1];
    const float* W1 = (const float*)d_in[2];
    const float* W3 = (const float*)d_in[3];
    const float* W2 = (const float*)d_in[4];
    const float* A1 = (const float*)d_in[5];
    const float* B1 = (const float*)d_in[6];
    const float* A3 = (const float*)d_in[7];
    const float* B3 = (const float*)d_in[8];
    const float* A2 = (const float*)d_in[9];
    const float* B2 = (const float*)d_in[10];
    float* out = (float*)d_out;                          // [N, D]
    float* logits = out + (size_t)N_TOK * D_DIM;         // [N, E]

    char* ws = (char*)d_ws;
    size_t off = 0;
    auto alloc = [&](size_t bytes) { char* p = ws + off; off += (bytes + 255) & ~(size_t)255; return p; };
    u16*   xb    = (u16*)alloc((size_t)N_TOK * D_DIM * 2);
    u16*   W13b  = (u16*)alloc((size_t)BN13 * D_DIM * 2);     // W1 | W3 | A1 | A3 (bf16)
    u16*   W2b   = (u16*)alloc((size_t)D_DIM * F_DIM * 2);
    u16*   base13= (u16*)alloc((size_t)N_TOK * BN13 * 2);     // bf16: base1 | base3 | l13
    int*   ridx  = (int*)alloc((size_t)N_TOK * 2 * 4);
    float* rwt   = (float*)alloc((size_t)N_TOK * 2 * 4);
    u16*   B1b   = (u16*)alloc((size_t)E_NUM * F_DIM * R_DIM * 2);  // bf16
    u16*   B3b   = (u16*)alloc((size_t)E_NUM * F_DIM * R_DIM * 2);  // bf16
    u16*   A2t   = (u16*)alloc((size_t)E_NUM * F_DIM * R_DIM * 2);  // bf16
    int*   counts= (int*)alloc(64);
    u32*   lists = (u32*)alloc((size_t)E_NUM * N_TOK * 4);
    u16*   sbuf  = (u16*)alloc((size_t)2 * N_TOK * F_DIM * 2);      // bf16
    u16*   smixb = (u16*)alloc((size_t)N_TOK * F_DIM * 2);          // bf16
    float* pbuf  = (float*)alloc((size_t)ZSPLIT * N_TOK * D_DIM * 4); // split-K partials
    (void)ws_size; (void)in_sizes; (void)n_in; (void)out_size;

    cvt_all<<<37760, 256, 0, stream>>>(x, W1, W3, A1, A3, W2, B1, B3,
                                       xb, W13b, W2b, B1b, B3b);
    a2_transpose<<<dim3(F_DIM / 256, E_NUM), 256, 0, stream>>>(A2, A2t);

    router_kernel<<<N_TOK, 256, 0, stream>>>(x, gw, logits, ridx, rwt);
    zero_counts<<<1, 64, 0, stream>>>(counts);
    build_lists<<<N_TOK / 256, 256, 0, stream>>>(ridx, counts, lists);

    // fused GEMM: [base1 | base3 | l13] = x @ [W1;W3;A1;A3]^T (bf16 out)
    // grid = (1024/256) * (11520/256) = 180, nk = 32
    gemm256<<<180, 512, 0, stream>>>(xb, W13b, (float*)base13,
                                     BN13, D_DIM, D_DIM, /*mode=*/1, /*ntm=*/4, /*ntn=*/45);

    act_v2b<<<dim3(NT, E_NUM, TC), 256, 0, stream>>>(base13, B1b, B3b,
                                                     lists, counts, rwt, sbuf);

    combine_kernel<<<(N_TOK * F_DIM / 8) / 256, 256, 0, stream>>>(sbuf, smixb);

    // smix @ W2^T -> split-K partials (NO atomics; private f32 slabs)
    // split-K z=8 (kslice = 704, nk = 11), grid = 4*8*8 = 256
    gemm256<<<256, 512, 0, stream>>>(smixb, W2b, pbuf,
                                     D_DIM, F_DIM, /*kslice=*/704, /*mode=*/0, /*ntm=*/4, /*ntn=*/8);

    // l2@B2 + sum of partials -> out (single writer of out)
    lora_down_v4<<<N_TOK, 256, 0, stream>>>(sbuf, A2t, ridx, B2, pbuf, out);
}

// Round 6
// 399.506 us; speedup vs baseline: 1.1672x; 1.0055x over previous
//
#include <hip/hip_runtime.h>

typedef unsigned int u32;
typedef unsigned short u16;

#define N_TOK 1024
#define D_DIM 2048
#define F_DIM 5632
#define E_NUM 8
#define R_DIM 16
#define LSCALE 2.0f
#define FT 256            // f-columns per act block
#define NT (F_DIM / FT)   // 22 F-tiles
#define TC 8              // token chunks per expert
#define BN13 11520        // fused B rows: W1(5632) + W3(5632) + A1(128) + A3(128)
#define ZSPLIT 8          // split-K factor for the W2 GEMM

typedef __bf16 bf16x8 __attribute__((ext_vector_type(8)));
typedef float f32x4 __attribute__((ext_vector_type(4)));
typedef u16 u16x8 __attribute__((ext_vector_type(8)));

__device__ inline u16 f2bf(float f) {
    u32 u = __builtin_bit_cast(u32, f);
    u32 r = (u + 0x7fffu + ((u >> 16) & 1u)) >> 16;
    return (u16)r;
}
__device__ inline float bf2f(u16 h) {
    u32 u = ((u32)h) << 16;
    return __builtin_bit_cast(float, u);
}

#define LGKM0() do { asm volatile("s_waitcnt lgkmcnt(0)" ::: "memory"); \
                     __builtin_amdgcn_sched_barrier(0); } while (0)
#define VMC(n)  do { asm volatile("s_waitcnt vmcnt(" #n ")" ::: "memory"); \
                     __builtin_amdgcn_sched_barrier(0); } while (0)

// ---------------- fused fp32 -> bf16 conversion for ALL weight tensors (1 launch) ----
__global__ __launch_bounds__(256) void cvt_all(const float* __restrict__ x,
                                               const float* __restrict__ W1,
                                               const float* __restrict__ W3,
                                               const float* __restrict__ A1,
                                               const float* __restrict__ A3,
                                               const float* __restrict__ W2,
                                               const float* __restrict__ B1,
                                               const float* __restrict__ B3,
                                               u16* __restrict__ xb,
                                               u16* __restrict__ w13,
                                               u16* __restrict__ w2b,
                                               u16* __restrict__ b1b,
                                               u16* __restrict__ b3b) {
    int i = blockIdx.x * 256 + threadIdx.x;
    const float* src;
    u16* dst;
    int off;
    if (i < 524288)       { src = x;  dst = xb;             off = i; }
    else if (i < 3407872) { src = W1; dst = w13;            off = i - 524288; }
    else if (i < 6291456) { src = W3; dst = w13 + 11534336; off = i - 3407872; }
    else if (i < 6356992) { src = A1; dst = w13 + 23068672; off = i - 6291456; }
    else if (i < 6422528) { src = A3; dst = w13 + 23330816; off = i - 6356992; }
    else if (i < 9306112) { src = W2; dst = w2b;            off = i - 6422528; }
    else if (i < 9486336) { src = B1; dst = b1b;            off = i - 9306112; }
    else                  { src = B3; dst = b3b;            off = i - 9486336; }
    float4 v = ((const float4*)src)[off];
    union { u16 h[4]; ushort4 u4; } o;
    o.h[0] = f2bf(v.x); o.h[1] = f2bf(v.y); o.h[2] = f2bf(v.z); o.h[3] = f2bf(v.w);
    ((ushort4*)dst)[off] = o.u4;
}

// ---------------- A2 (E,R,F) fp32 -> A2t (E,F,R) bf16 ----------------
__global__ __launch_bounds__(256) void a2_transpose(const float* __restrict__ A2,
                                                    u16* __restrict__ A2t) {
    int e = blockIdx.y;
    int f = blockIdx.x * 256 + threadIdx.x;
    u16 row[16];
#pragma unroll
    for (int r = 0; r < 16; ++r)
        row[r] = f2bf(A2[((size_t)e * R_DIM + r) * F_DIM + f]);
    u16* dst = A2t + ((size_t)e * F_DIM + f) * 16;
#pragma unroll
    for (int q = 0; q < 2; ++q)
        ((ulonglong2*)dst)[q] = ((ulonglong2*)row)[q];
}

// ---------------- router: logits + softmax + top2 ----------------
__global__ __launch_bounds__(256) void router_kernel(const float* __restrict__ x,
                                                     const float* __restrict__ gw,
                                                     float* __restrict__ logits,
                                                     int* __restrict__ ridx,
                                                     float* __restrict__ rw) {
    int n = blockIdx.x;
    int tid = threadIdx.x;
    float part[E_NUM];
#pragma unroll
    for (int e = 0; e < E_NUM; ++e) part[e] = 0.f;
    const float* xr = x + (size_t)n * D_DIM;
    for (int d = tid; d < D_DIM; d += 256) {
        float xv = xr[d];
#pragma unroll
        for (int e = 0; e < E_NUM; ++e) part[e] += xv * gw[e * D_DIM + d];
    }
    __shared__ float sh[E_NUM][256];
#pragma unroll
    for (int e = 0; e < E_NUM; ++e) sh[e][tid] = part[e];
    __syncthreads();
    for (int off = 128; off > 0; off >>= 1) {
        if (tid < off) {
#pragma unroll
            for (int e = 0; e < E_NUM; ++e) sh[e][tid] += sh[e][tid + off];
        }
        __syncthreads();
    }
    if (tid == 0) {
        float lg[E_NUM], p[E_NUM];
        float mx = -1e30f;
        for (int e = 0; e < E_NUM; ++e) {
            lg[e] = sh[e][0];
            logits[n * E_NUM + e] = lg[e];
            if (lg[e] > mx) mx = lg[e];
        }
        float s = 0.f;
        for (int e = 0; e < E_NUM; ++e) { p[e] = expf(lg[e] - mx); s += p[e]; }
        for (int e = 0; e < E_NUM; ++e) p[e] /= s;
        int i1 = 0;
        for (int e = 1; e < E_NUM; ++e) if (p[e] > p[i1]) i1 = e;
        int i2 = (i1 == 0) ? 1 : 0;
        for (int e = 0; e < E_NUM; ++e) if (e != i1 && p[e] > p[i2]) i2 = e;
        float t = p[i1] + p[i2];
        ridx[n * 2] = i1; ridx[n * 2 + 1] = i2;
        rw[n * 2] = p[i1] / t; rw[n * 2 + 1] = p[i2] / t;
    }
}

// ---------------- expert token-list build (counts pre-zeroed via memset) ------------
__global__ __launch_bounds__(256) void build_lists(const int* __restrict__ ridx,
                                                   int* __restrict__ counts,
                                                   u32* __restrict__ lists) {
    int n = blockIdx.x * 256 + threadIdx.x;
    if (n >= N_TOK) return;
#pragma unroll
    for (int k = 0; k < 2; ++k) {
        int e = ridx[n * 2 + k];
        int slot = atomicAdd(&counts[e], 1);
        lists[e * N_TOK + slot] = (u32)n | ((u32)k << 16);
    }
}

// ---------------- 256x256-tile bf16 MFMA GEMM, 4-phase/K-tile, 1 barrier/phase ------
// C[M,N] = A[M,K] @ B[N,K]^T. 512 threads = 8 waves (2M x 4N), wave owns 128x64.
// R6: ONE barrier per phase (was 2). Hazard proof: every ds_read is followed by a
// same-phase lgkmcnt(0) BEFORE the phase-end barrier, so at any phase start all
// waves' prior-phase LDS reads have COMPLETED (not just issued). Stage targets:
//   a: A(t+1)h0 -> other A buf (readers of that buf finished at tile t-1) SAFE
//   b: A(t+1)h1 -> same                                                   SAFE
//   c: B(t+2)h0 -> current B buf; all B(t) reads completed by b's barrier SAFE
//   d: B(t+2)h1 -> same                                                   SAFE
// vmcnt ledger unchanged from R5 (2 loads per stageHalf per thread):
//   tile start: B(t+1):4 in flight; +2 per phase; VMC(4)@d retires
//   B(t+1)+A(t+1) -> tile t+1 landed. VMC(0) at t==nk-2. Prologue A0,B0,B1;VMC(4).
// Removing the mid-phase barrier also lets waves slide within a phase so one
// wave's ds_reads overlap another's MFMA burst (LDS port || MFMA pipe).
// T2 swizzle: SQ_LDS_BANK_CONFLICT = 0 (verified R3-R5).
// mode: 0 = f32 store to private split-K partial slab (C + zt*ntm*256*N),
//       1 = bf16 store (zt must be 0).
__global__ __launch_bounds__(512, 2) void gemm256(const u16* __restrict__ A,
                                                  const u16* __restrict__ B,
                                                  float* __restrict__ C,
                                                  int N, int K, int kslice,
                                                  int mode, int ntm, int ntn) {
    // [mat][buf][ksplane][row*32+col] u16  -> 128 KiB
    __shared__ __align__(16) u16 lds[2][2][2][256 * 32];

    // --- bijective XCD-chunked swizzle ---
    const int nb = gridDim.x;
    const int fb = blockIdx.x;
    const int qq = nb >> 3, rr = nb & 7;
    const int xcd = fb & 7, lo = fb >> 3;
    const int wg = (xcd < rr ? xcd * (qq + 1) : rr * (qq + 1) + (xcd - rr) * qq) + lo;

    const int mt = wg % ntm;
    const int t2 = wg / ntm;
    const int nt = t2 % ntn;
    const int zt = t2 / ntn;

    const int bm0 = mt * 256;
    const int bn0 = nt * 256;
    const int kb = zt * kslice;

    const int tid = threadIdx.x;
    const int lane = tid & 63;
    const int wave = tid >> 6;
    const int quad = lane >> 4;
    const int l16 = lane & 15;
    const int swz = (l16 & 8) << 1;     // elem-offset XOR for ds_read (row&8 == l16&8)
    const int wm = (wave >> 2) * 128;   // 0 or 128
    const int wn = (wave & 3) * 64;     // 0,64,128,192

    f32x4 zero = {0.f, 0.f, 0.f, 0.f};
    f32x4 acc[8][4];
#pragma unroll
    for (int i = 0; i < 8; ++i)
#pragma unroll
        for (int j = 0; j < 4; ++j) acc[i][j] = zero;

    // stage one half-tile (128 rows x 64 cols bf16 of one matrix) = 2 loads/thread
    auto stageHalf = [&](const u16* __restrict__ G, int mat, int buf, int h,
                         int k0, int rowBase) {
#pragma unroll
        for (int j = 0; j < 2; ++j) {
            int seg = wave * 2 + j;         // 0..15
            int plane = seg >> 3;
            int rb = seg & 7;
            int r = h * 128 + rb * 16 + (lane >> 2);
            int slot = lane & 3;
            int gcol = k0 + plane * 32 + ((slot * 8) ^ ((r & 8) << 1));
            const u16* gp = G + (size_t)(rowBase + r) * K + gcol;
            u16* lp = &lds[mat][buf][plane][(h * 128 + rb * 16) * 32] + lane * 8;
            __builtin_amdgcn_global_load_lds((const __attribute__((address_space(1))) u32*)gp,
                                             (__attribute__((address_space(3))) u32*)lp,
                                             16, 0, 0);
        }
    };

    // fragment loaders (swizzled ds_read addresses)
    auto ldA = [&](int buf, int ks, int mi) -> bf16x8 {
        return *(const bf16x8*)&lds[0][buf][ks]
            [(wm + mi * 16 + l16) * 32 + ((quad * 8) ^ swz)];
    };
    auto ldB = [&](int buf, int ks, int ni) -> bf16x8 {
        return *(const bf16x8*)&lds[1][buf][ks]
            [(wn + ni * 16 + l16) * 32 + ((quad * 8) ^ swz)];
    };

    const int nk = kslice >> 6;

    // ---- prologue: A(t0) both halves, B(t0) both halves, B(t1) both halves ----
    stageHalf(A, 0, 0, 0, kb, bm0);
    stageHalf(A, 0, 0, 1, kb, bm0);
    stageHalf(B, 1, 0, 0, kb, bn0);
    stageHalf(B, 1, 0, 1, kb, bn0);
    stageHalf(B, 1, 1, 0, kb + 64, bn0);
    stageHalf(B, 1, 1, 1, kb + 64, bn0);
    VMC(4);                      // tile0 landed; B(t1) (4 loads) still in flight
    __builtin_amdgcn_s_barrier();

    for (int t = 0; t < nk; ++t) {
        const int buf = t & 1;
        const int k0 = kb + t * 64;
        bf16x8 bq0[4], bq1[4];   // B frags ks0 / ks1, live across phases

        // ===== phase a: read A(mi0-3,ks0)+B(ks0); MFMA mi0-3*ks0; stage A(t+1)h0 ====
        {
            bf16x8 av[4];
#pragma unroll
            for (int mi = 0; mi < 4; ++mi) av[mi] = ldA(buf, 0, mi);
#pragma unroll
            for (int ni = 0; ni < 4; ++ni) bq0[ni] = ldB(buf, 0, ni);
            if (t + 1 < nk) stageHalf(A, 0, buf ^ 1, 0, k0 + 64, bm0);
            LGKM0();
            __builtin_amdgcn_s_setprio(1);
#pragma unroll
            for (int mi = 0; mi < 4; ++mi)
#pragma unroll
                for (int ni = 0; ni < 4; ++ni)
                    acc[mi][ni] = __builtin_amdgcn_mfma_f32_16x16x32_bf16(
                        av[mi], bq0[ni], acc[mi][ni], 0, 0, 0);
            __builtin_amdgcn_s_setprio(0);
            __builtin_amdgcn_s_barrier();
        }

        // ===== phase b: read A(mi4-7,ks0)+B(ks1); MFMA mi4-7*ks0; stage A(t+1)h1 ====
        {
            bf16x8 av[4];
#pragma unroll
            for (int mi = 0; mi < 4; ++mi) av[mi] = ldA(buf, 0, 4 + mi);
#pragma unroll
            for (int ni = 0; ni < 4; ++ni) bq1[ni] = ldB(buf, 1, ni);
            if (t + 1 < nk) stageHalf(A, 0, buf ^ 1, 1, k0 + 64, bm0);
            LGKM0();
            __builtin_amdgcn_s_setprio(1);
#pragma unroll
            for (int mi = 0; mi < 4; ++mi)
#pragma unroll
                for (int ni = 0; ni < 4; ++ni)
                    acc[4 + mi][ni] = __builtin_amdgcn_mfma_f32_16x16x32_bf16(
                        av[mi], bq0[ni], acc[4 + mi][ni], 0, 0, 0);
            __builtin_amdgcn_s_setprio(0);
            __builtin_amdgcn_s_barrier();
        }

        // ===== phase c: read A(mi0-3,ks1); MFMA mi0-3*ks1; stage B(t+2)h0 ===========
        {
            bf16x8 av[4];
#pragma unroll
            for (int mi = 0; mi < 4; ++mi) av[mi] = ldA(buf, 1, mi);
            if (t + 2 < nk) stageHalf(B, 1, buf, 0, k0 + 128, bn0);
            LGKM0();
            __builtin_amdgcn_s_setprio(1);
#pragma unroll
            for (int mi = 0; mi < 4; ++mi)
#pragma unroll
                for (int ni = 0; ni < 4; ++ni)
                    acc[mi][ni] = __builtin_amdgcn_mfma_f32_16x16x32_bf16(
                        av[mi], bq1[ni], acc[mi][ni], 0, 0, 0);
            __builtin_amdgcn_s_setprio(0);
            __builtin_amdgcn_s_barrier();
        }

        // ===== phase d: read A(mi4-7,ks1); MFMA mi4-7*ks1; stage B(t+2)h1; VMC ======
        {
            bf16x8 av[4];
#pragma unroll
            for (int mi = 0; mi < 4; ++mi) av[mi] = ldA(buf, 1, 4 + mi);
            if (t + 2 < nk) stageHalf(B, 1, buf, 1, k0 + 128, bn0);
            LGKM0();
            __builtin_amdgcn_s_setprio(1);
#pragma unroll
            for (int mi = 0; mi < 4; ++mi)
#pragma unroll
                for (int ni = 0; ni < 4; ++ni)
                    acc[4 + mi][ni] = __builtin_amdgcn_mfma_f32_16x16x32_bf16(
                        av[mi], bq1[ni], acc[4 + mi][ni], 0, 0, 0);
            __builtin_amdgcn_s_setprio(0);
            if (t < nk - 2)       { VMC(4); }   // tile t+1 fully landed
            else if (t == nk - 2) { VMC(0); }   // final tile fully landed
            __builtin_amdgcn_s_barrier();
        }
    }

    // epilogue: mode 0 -> private f32 partial slab (no atomics); mode 1 -> bf16
    float* Cz = C + (size_t)zt * ntm * 256 * N;
#pragma unroll
    for (int mi = 0; mi < 8; ++mi)
#pragma unroll
        for (int ni = 0; ni < 4; ++ni) {
            int col = bn0 + wn + ni * 16 + l16;
#pragma unroll
            for (int i = 0; i < 4; ++i) {
                int row = bm0 + wm + mi * 16 + quad * 4 + i;
                if (mode == 1) {
                    ((u16*)C)[(size_t)row * N + col] = f2bf(acc[mi][ni][i]);
                } else {
                    Cz[(size_t)row * N + col] = acc[mi][ni][i];
                }
            }
        }
}

// ---------------- expert-grouped activation kernel ----------------
__global__ __launch_bounds__(256) void act_v2b(const u16* __restrict__ base13,
                                               const u16* __restrict__ B1b,
                                               const u16* __restrict__ B3b,
                                               const u32* __restrict__ lists,
                                               const int* __restrict__ counts,
                                               const float* __restrict__ rw,
                                               u16* __restrict__ sbuf) {
    const int ft = blockIdx.x;
    const int e  = blockIdx.y;
    const int z  = blockIdx.z;
    const int tid = threadIdx.x;
    const int lane = tid & 63;
    const int wave = tid >> 6;
    const int f_lane = ft * FT + lane * 4;

    u16x8 w1c[8], w3c[8];
    {
        const u16* p1 = B1b + ((size_t)e * F_DIM + f_lane) * 16;
        const u16* p3 = B3b + ((size_t)e * F_DIM + f_lane) * 16;
#pragma unroll
        for (int c = 0; c < 8; ++c) {
            w1c[c] = *(const u16x8*)(p1 + c * 8);
            w3c[c] = *(const u16x8*)(p3 + c * 8);
        }
    }

    const int T = counts[e];
    for (int i = z * 4 + wave; i < T; i += TC * 4) {
        u32 ent = lists[e * N_TOK + i];
        int n = (int)(ent & 0xFFFFu);
        int k = (int)(ent >> 16);
        float wt = rw[n * 2 + k];

        float la1[16], la3[16];
        {
            const u16x8* pl1 = (const u16x8*)(base13 + (size_t)n * BN13 + 11264 + e * 16);
            const u16x8* pl3 = (const u16x8*)(base13 + (size_t)n * BN13 + 11392 + e * 16);
#pragma unroll
            for (int h = 0; h < 2; ++h) {
                u16x8 t1 = pl1[h], t3 = pl3[h];
#pragma unroll
                for (int qq = 0; qq < 8; ++qq) {
                    la1[h * 8 + qq] = LSCALE * bf2f(t1[qq]);
                    la3[h * 8 + qq] = LSCALE * bf2f(t3[qq]);
                }
            }
        }

        ushort4 b1u = *(const ushort4*)(base13 + (size_t)n * BN13 + f_lane);
        ushort4 b3u = *(const ushort4*)(base13 + (size_t)n * BN13 + 5632 + f_lane);
        const u16* b1p = (const u16*)&b1u;
        const u16* b3p = (const u16*)&b3u;

        u16 sv[4];
#pragma unroll
        for (int j = 0; j < 4; ++j) {
            float h1 = bf2f(b1p[j]);
            float h3 = bf2f(b3p[j]);
#pragma unroll
            for (int qq = 0; qq < 8; ++qq) {
                h1 += la1[qq] * bf2f(w1c[2 * j][qq]);
                h3 += la3[qq] * bf2f(w3c[2 * j][qq]);
            }
#pragma unroll
            for (int qq = 0; qq < 8; ++qq) {
                h1 += la1[8 + qq] * bf2f(w1c[2 * j + 1][qq]);
                h3 += la3[8 + qq] * bf2f(w3c[2 * j + 1][qq]);
            }
            float sg = h1 / (1.f + __expf(-h1));
            sv[j] = f2bf(wt * sg * h3);
        }
        *(ushort4*)(sbuf + ((size_t)k * N_TOK + n) * F_DIM + f_lane) = *(ushort4*)sv;
    }
}

// ---------------- combine: smix = sbuf0 + sbuf1 ----------------
__global__ __launch_bounds__(256) void combine_kernel(const u16* __restrict__ sbuf,
                                                      u16* __restrict__ smix) {
    size_t i = ((size_t)blockIdx.x * 256 + threadIdx.x) * 8;
    u16x8 a = *(const u16x8*)(sbuf + i);
    u16x8 b = *(const u16x8*)(sbuf + (size_t)N_TOK * F_DIM + i);
    u16x8 o;
#pragma unroll
    for (int q = 0; q < 8; ++q) o[q] = f2bf(bf2f(a[q]) + bf2f(b[q]));
    *(u16x8*)(smix + i) = o;
}

// ---------------- lora_down_v4: l2@B2 + sum of split-K partials -> out --------------
__global__ __launch_bounds__(256) void lora_down_v4(const u16* __restrict__ sbuf,
                                                    const u16* __restrict__ A2t,
                                                    const int* __restrict__ ridx,
                                                    const float* __restrict__ B2,
                                                    const float* __restrict__ pbuf,
                                                    float* __restrict__ out) {
    const int n = blockIdx.x, tid = threadIdx.x;
    __shared__ float part[2][32][16];
    __shared__ float fin[2][16];
    __shared__ int se[2];
    if (tid < 2) se[tid] = ridx[n * 2 + tid];
    __syncthreads();

    {
        const int k = tid >> 7;
        const int tt = tid & 127;
        const int rq = tt & 3;
        const int fc = tt >> 2;
        const int e = se[k];
        const u16* srow = sbuf + ((size_t)k * N_TOK + n) * F_DIM + fc * 176;
        const u16* arow = A2t + ((size_t)e * F_DIM + fc * 176) * 16 + rq * 4;
        float acc0 = 0.f, acc1 = 0.f, acc2 = 0.f, acc3 = 0.f;
#pragma unroll 4
        for (int f = 0; f < 176; ++f) {
            float sv = bf2f(srow[f]);
            ushort4 wr = *(const ushort4*)(arow + (size_t)f * 16);
            acc0 += sv * bf2f(wr.x);
            acc1 += sv * bf2f(wr.y);
            acc2 += sv * bf2f(wr.z);
            acc3 += sv * bf2f(wr.w);
        }
        part[k][fc][rq * 4 + 0] = acc0;
        part[k][fc][rq * 4 + 1] = acc1;
        part[k][fc][rq * 4 + 2] = acc2;
        part[k][fc][rq * 4 + 3] = acc3;
    }
    __syncthreads();
    if (tid < 32) {
        int k = tid >> 4, r = tid & 15;
        float s = 0.f;
#pragma unroll
        for (int fc = 0; fc < 32; ++fc) s += part[k][fc][r];
        fin[k][r] = LSCALE * s;
    }
    __syncthreads();

    float a0[16], a1v[16];
#pragma unroll
    for (int r = 0; r < 16; ++r) { a0[r] = fin[0][r]; a1v[r] = fin[1][r]; }
    const float* B2a = B2 + (size_t)se[0] * D_DIM * R_DIM;
    const float* B2b = B2 + (size_t)se[1] * D_DIM * R_DIM;
    const float* prow = pbuf + (size_t)n * D_DIM;
    float* orow = out + (size_t)n * D_DIM;
    for (int d = tid; d < D_DIM; d += 256) {
        const float4* pa = (const float4*)(B2a + (size_t)d * 16);
        const float4* pb = (const float4*)(B2b + (size_t)d * 16);
        float acc = 0.f;
#pragma unroll
        for (int q = 0; q < 4; ++q) {
            float4 va = pa[q];
            acc += a0[q * 4] * va.x + a0[q * 4 + 1] * va.y +
                   a0[q * 4 + 2] * va.z + a0[q * 4 + 3] * va.w;
            float4 vb = pb[q];
            acc += a1v[q * 4] * vb.x + a1v[q * 4 + 1] * vb.y +
                   a1v[q * 4 + 2] * vb.z + a1v[q * 4 + 3] * vb.w;
        }
        // fold the ZSPLIT split-K partials (L3-resident, written just before)
        float ps = 0.f;
#pragma unroll
        for (int z = 0; z < ZSPLIT; ++z)
            ps += prow[(size_t)z * N_TOK * D_DIM + d];
        orow[d] = acc + ps;
    }
}

extern "C" void kernel_launch(void* const* d_in, const int* in_sizes, int n_in,
                              void* d_out, int out_size, void* d_ws, size_t ws_size,
                              hipStream_t stream) {
    const float* x  = (const float*)d_in[0];
    const float* gw = (const float*)d_in[1];
    const float* W1 = (const float*)d_in[2];
    const float* W3 = (const float*)d_in[3];
    const float* W2 = (const float*)d_in[4];
    const float* A1 = (const float*)d_in[5];
    const float* B1 = (const float*)d_in[6];
    const float* A3 = (const float*)d_in[7];
    const float* B3 = (const float*)d_in[8];
    const float* A2 = (const float*)d_in[9];
    const float* B2 = (const float*)d_in[10];
    float* out = (float*)d_out;                          // [N, D]
    float* logits = out + (size_t)N_TOK * D_DIM;         // [N, E]

    char* ws = (char*)d_ws;
    size_t off = 0;
    auto alloc = [&](size_t bytes) { char* p = ws + off; off += (bytes + 255) & ~(size_t)255; return p; };
    u16*   xb    = (u16*)alloc((size_t)N_TOK * D_DIM * 2);
    u16*   W13b  = (u16*)alloc((size_t)BN13 * D_DIM * 2);     // W1 | W3 | A1 | A3 (bf16)
    u16*   W2b   = (u16*)alloc((size_t)D_DIM * F_DIM * 2);
    u16*   base13= (u16*)alloc((size_t)N_TOK * BN13 * 2);     // bf16: base1 | base3 | l13
    int*   ridx  = (int*)alloc((size_t)N_TOK * 2 * 4);
    float* rwt   = (float*)alloc((size_t)N_TOK * 2 * 4);
    u16*   B1b   = (u16*)alloc((size_t)E_NUM * F_DIM * R_DIM * 2);  // bf16
    u16*   B3b   = (u16*)alloc((size_t)E_NUM * F_DIM * R_DIM * 2);  // bf16
    u16*   A2t   = (u16*)alloc((size_t)E_NUM * F_DIM * R_DIM * 2);  // bf16
    int*   counts= (int*)alloc(64);
    u32*   lists = (u32*)alloc((size_t)E_NUM * N_TOK * 4);
    u16*   sbuf  = (u16*)alloc((size_t)2 * N_TOK * F_DIM * 2);      // bf16
    u16*   smixb = (u16*)alloc((size_t)N_TOK * F_DIM * 2);          // bf16
    float* pbuf  = (float*)alloc((size_t)ZSPLIT * N_TOK * D_DIM * 4); // split-K partials
    (void)ws_size; (void)in_sizes; (void)n_in; (void)out_size;

    cvt_all<<<37760, 256, 0, stream>>>(x, W1, W3, A1, A3, W2, B1, B3,
                                       xb, W13b, W2b, B1b, B3b);
    a2_transpose<<<dim3(F_DIM / 256, E_NUM), 256, 0, stream>>>(A2, A2t);

    router_kernel<<<N_TOK, 256, 0, stream>>>(x, gw, logits, ridx, rwt);
    hipMemsetAsync(counts, 0, 64, stream);
    build_lists<<<N_TOK / 256, 256, 0, stream>>>(ridx, counts, lists);

    // fused GEMM: [base1 | base3 | l13] = x @ [W1;W3;A1;A3]^T (bf16 out)
    // grid = (1024/256) * (11520/256) = 180, nk = 32
    gemm256<<<180, 512, 0, stream>>>(xb, W13b, (float*)base13,
                                     BN13, D_DIM, D_DIM, /*mode=*/1, /*ntm=*/4, /*ntn=*/45);

    act_v2b<<<dim3(NT, E_NUM, TC), 256, 0, stream>>>(base13, B1b, B3b,
                                                     lists, counts, rwt, sbuf);

    combine_kernel<<<(N_TOK * F_DIM / 8) / 256, 256, 0, stream>>>(sbuf, smixb);

    // smix @ W2^T -> split-K partials (NO atomics; private f32 slabs)
    // split-K z=8 (kslice = 704, nk = 11), grid = 4*8*8 = 256
    gemm256<<<256, 512, 0, stream>>>(smixb, W2b, pbuf,
                                     D_DIM, F_DIM, /*kslice=*/704, /*mode=*/0, /*ntm=*/4, /*ntn=*/8);

    // l2@B2 + sum of partials -> out (single writer of out)
    lora_down_v4<<<N_TOK, 256, 0, stream>>>(sbuf, A2t, ridx, B2, pbuf, out);
}